// Round 1
// baseline (2709.311 us; speedup 1.0000x reference)
//
#include <hip/hip_runtime.h>
#include <math.h>

#define NNODES 100000
#define NT0 60000
#define NT1 40000
#define FD0 128
#define FD1 64
#define HID 64
#define HEADS 8
#define OUTD 16
#define AVEC 128
#define NE 250000
#define NG 8192
#define NB 8192

// workspace layout (float offsets)
#define OFF_TF      0ull          // 100000*64      = 6,400,000
#define OFF_FINALS  6400000ull    // 2*3*32*2       = 384 (pad to 512)
#define OFF_ACC     6400512ull    // 2*128          = 256
#define OFF_BETA    6400768ull    // 2 (pad 256)
#define OFF_A       6401024ull    // NE*8           = 2,000,000
#define OFF_M       8401024ull    // NG*8 (uint)    = 65,536
#define OFF_S       8466560ull    // NG*8           = 65,536
#define OFF_U       8532096ull    // NG*512         = 4,194,304
#define OFF_OUT0    12726400ull   // NB*512         = 4,194,304
#define OFF_OUT1    16920704ull   // NB*512         = 4,194,304
// total = 21,115,008 floats = 84,460,032 bytes

__device__ __forceinline__ unsigned fkey(float x){
  unsigned b = __float_as_uint(x);
  return (b & 0x80000000u) ? ~b : (b | 0x80000000u);
}
__device__ __forceinline__ float funkey(unsigned k){
  return (k & 0x80000000u) ? __uint_as_float(k & 0x7FFFFFFFu) : __uint_as_float(~k);
}

// ---- prep: normalize r_vec, build finals for both metapaths, zero acc ----
__global__ void k_prep(const float* __restrict__ r_vec, float* __restrict__ finals,
                       float* __restrict__ acc, float* __restrict__ beta){
  int j = threadIdx.x;
  if (j < 32){
    const float2* rv = (const float2*)r_vec;
    float2 r0 = rv[j];        // relation 0, pair j
    float2 r1 = rv[32 + j];   // relation 1
    float n0 = rsqrtf(r0.x*r0.x + r0.y*r0.y);
    float n1 = rsqrtf(r1.x*r1.x + r1.y*r1.y);
    r0.x *= n0; r0.y *= n0; r1.x *= n1; r1.y *= n1;
    // rv_full: [0]=r0, [1]=conj(r0), [2]=r1, [3]=conj(r1)
    float2 rf1 = make_float2(r0.x, -r0.y);
    float2 rf3 = make_float2(r1.x, -r1.y);
    float2* F = (float2*)finals;  // [2][3][32] complex
    // metapath 0: etypes [0,1]: finals = [rf1*rf0, rf1, 1]
    F[(0*3+2)*32 + j] = make_float2(1.f, 0.f);
    F[(0*3+1)*32 + j] = rf1;
    F[(0*3+0)*32 + j] = make_float2(rf1.x*r0.x - rf1.y*r0.y, rf1.x*r0.y + rf1.y*r0.x);
    // metapath 1: etypes [2,3]: finals = [rf3*rf2, rf3, 1]
    F[(1*3+2)*32 + j] = make_float2(1.f, 0.f);
    F[(1*3+1)*32 + j] = rf3;
    F[(1*3+0)*32 + j] = make_float2(rf3.x*r1.x - rf3.y*r1.y, rf3.x*r1.y + rf3.y*r1.x);
  }
  for (int t = threadIdx.x; t < 256; t += 64) acc[t] = 0.f;
  if (threadIdx.x < 2) beta[threadIdx.x] = 0.f;
}

// ---- per-type linear into dense node table ----
__global__ void k_transform(const float* __restrict__ feat, const float* __restrict__ W,
                            const float* __restrict__ bias, const int* __restrict__ idx,
                            int n_nodes, int F, float* __restrict__ tf){
  int t = blockIdx.x*blockDim.x + threadIdx.x;
  int node = t >> 6; int d = t & 63;
  if (node >= n_nodes) return;
  const float4* f4 = (const float4*)(feat + (size_t)node * F);
  const float4* w4 = (const float4*)(W + (size_t)d * F);
  float s = bias[d];
  int nf4 = F >> 2;
  for (int f = 0; f < nf4; ++f){
    float4 a = f4[f], b = w4[f];
    s += a.x*b.x + a.y*b.y + a.z*b.z + a.w*b.w;
  }
  tf[(size_t)idx[node]*HID + d] = s;
}

// ---- init segment buffers ----
__global__ void k_init(unsigned* __restrict__ m, float* __restrict__ s, float* __restrict__ u){
  int t = blockIdx.x*blockDim.x + threadIdx.x;
  if (t < NG*HEADS){ m[t] = 0x007FFFFFu; s[t] = 0.f; }  // key(-inf)
  if (t < NG*HEADS*HID) u[t] = 0.f;
}

// shared edge-h computation: 32 lanes per edge, lane j owns complex pair j
__device__ __forceinline__ void edge_h(const float* __restrict__ tf, const int* __restrict__ mpi,
                                       const float* __restrict__ finals_p,
                                       int e, int j, float& hre, float& him){
  int n0 = mpi[e*3+0], n1 = mpi[e*3+1], n2 = mpi[e*3+2];
  const float2* F2 = (const float2*)finals_p;
  float2 f0 = F2[j], f1 = F2[32 + j];   // pos 2 rotation is identity
  const float2* tf2 = (const float2*)tf;
  float2 v0 = tf2[(size_t)n0*32 + j];
  float2 v1 = tf2[(size_t)n1*32 + j];
  float2 v2 = tf2[(size_t)n2*32 + j];
  hre = (v0.x*f0.x - v0.y*f0.y) + (v1.x*f1.x - v1.y*f1.y) + v2.x;
  him = (v0.x*f0.y + v0.y*f0.x) + (v1.x*f1.y + v1.y*f1.x) + v2.y;
  hre *= (1.f/3.f); him *= (1.f/3.f);
}

// ---- pass A: attention logits + segment max ----
__global__ void k_passA(const float* __restrict__ tf, const int* __restrict__ mpi,
                        const int* __restrict__ dst, const float* __restrict__ finals_p,
                        const float* __restrict__ attn, float* __restrict__ a_buf,
                        unsigned* __restrict__ m_buf){
  int t = blockIdx.x*blockDim.x + threadIdx.x;
  int e = t >> 5, j = t & 31;
  if (e >= NE) return;
  float hre, him;
  edge_h(tf, mpi, finals_p, e, j, hre, him);
  float p[8];
  const float2* at2 = (const float2*)attn;
  #pragma unroll
  for (int k = 0; k < 8; ++k){
    float2 aw = at2[k*32 + j];
    p[k] = hre*aw.x + him*aw.y;
  }
  #pragma unroll
  for (int mask = 1; mask < 32; mask <<= 1){
    #pragma unroll
    for (int k = 0; k < 8; ++k) p[k] += __shfl_xor(p[k], mask, 32);
  }
  if (j < 8){
    float v = p[0];
    #pragma unroll
    for (int k = 1; k < 8; ++k) v = (j == k) ? p[k] : v;
    float a = v > 0.f ? v : 0.01f*v;      // leaky_relu
    a_buf[(size_t)e*8 + j] = a;
    int dv = dst[e];
    atomicMax(&m_buf[dv*8 + j], fkey(a));
  }
}

// ---- pass B: exp, segment sum, unnormalized weighted scatter ----
__global__ void k_passB(const float* __restrict__ tf, const int* __restrict__ mpi,
                        const int* __restrict__ dst, const float* __restrict__ finals_p,
                        const float* __restrict__ a_buf, const unsigned* __restrict__ m_buf,
                        float* __restrict__ s_buf, float* __restrict__ u_buf){
  int t = blockIdx.x*blockDim.x + threadIdx.x;
  int e = t >> 5, j = t & 31;
  if (e >= NE) return;
  float hre, him;
  edge_h(tf, mpi, finals_p, e, j, hre, him);
  int dv = dst[e];
  float ex = 0.f;
  if (j < 8){
    float a = a_buf[(size_t)e*8 + j];
    float mv = funkey(m_buf[dv*8 + j]);
    ex = expf(a - mv);
    atomicAdd(&s_buf[dv*8 + j], ex);
  }
  float* ub = u_buf + (size_t)dv*512;
  #pragma unroll
  for (int k = 0; k < 8; ++k){
    float exk = __shfl(ex, k, 32);
    atomicAdd(&ub[k*64 + 2*j],     exk*hre);
    atomicAdd(&ub[k*64 + 2*j + 1], exk*him);
  }
}

// ---- gather targets, normalize, elu ----
__global__ void k_out(const float* __restrict__ u, const float* __restrict__ s,
                      const int* __restrict__ target, float* __restrict__ outp){
  int t = blockIdx.x*blockDim.x + threadIdx.x;
  if (t >= NB*512) return;
  int b = t >> 9, c = t & 511;
  int g = target[b];
  float sv = s[g*8 + (c >> 6)];
  float v = sv > 0.f ? u[(size_t)g*512 + c] / sv : 0.f;
  outp[t] = v > 0.f ? v : expm1f(v);   // elu
}

// ---- metapath-attention: accumulate mean of tanh(fc1 @ out + b) ----
__global__ void k_s1(const float* __restrict__ outp, const float* __restrict__ fc1_w,
                     const float* __restrict__ fc1_b, float* __restrict__ acc_p){
  __shared__ float lds[512];
  int t = threadIdx.x;  // 128
  float local = 0.f;
  for (int b = blockIdx.x; b < NB; b += gridDim.x){
    ((float4*)lds)[t] = ((const float4*)(outp + (size_t)b*512))[t];
    __syncthreads();
    float s = fc1_b[t];
    const float4* w = (const float4*)(fc1_w + (size_t)t*512);
    #pragma unroll 4
    for (int i = 0; i < 128; ++i){
      float4 a = ((float4*)lds)[i], ww = w[i];
      s += a.x*ww.x + a.y*ww.y + a.z*ww.z + a.w*ww.w;
    }
    local += tanhf(s);
    __syncthreads();
  }
  atomicAdd(&acc_p[t], local);
}

// ---- beta softmax over 2 metapaths ----
__global__ void k_beta(const float* __restrict__ acc, const float* __restrict__ fc2_w,
                       float* __restrict__ beta){
  int t = threadIdx.x;  // 64
  float s0 = acc[t]*fc2_w[t] + acc[t+64]*fc2_w[t+64];
  float s1 = acc[128+t]*fc2_w[t] + acc[192+t]*fc2_w[t+64];
  #pragma unroll
  for (int mask = 1; mask < 64; mask <<= 1){
    s0 += __shfl_xor(s0, mask, 64);
    s1 += __shfl_xor(s1, mask, 64);
  }
  if (t == 0){
    float z0 = s0 / (float)NB, z1 = s1 / (float)NB;
    float mz = fmaxf(z0, z1);
    float e0 = expf(z0 - mz), e1 = expf(z1 - mz);
    float inv = 1.f / (e0 + e1);
    beta[0] = e0*inv; beta[1] = e1*inv;
  }
}

// ---- hagg + logits ----
__global__ void k_final(const float* __restrict__ out0, const float* __restrict__ out1,
                        const float* __restrict__ beta, const float* __restrict__ fc_w,
                        const float* __restrict__ fc_b, float* __restrict__ d_out){
  __shared__ float lds[512];
  int b = blockIdx.x, t = threadIdx.x;  // 512 threads
  float b0 = beta[0], b1 = beta[1];
  float h = b0*out0[(size_t)b*512 + t] + b1*out1[(size_t)b*512 + t];
  lds[t] = h;
  d_out[(size_t)NB*OUTD + (size_t)b*512 + t] = h;   // hagg after logits block
  __syncthreads();
  int o = t >> 5, j = t & 31;
  float s = 0.f;
  const float* w = fc_w + o*512;
  for (int d = j; d < 512; d += 32) s += lds[d]*w[d];
  #pragma unroll
  for (int mask = 1; mask < 32; mask <<= 1) s += __shfl_xor(s, mask, 32);
  if (j == 0) d_out[(size_t)b*OUTD + o] = s + fc_b[o];
}

extern "C" void kernel_launch(void* const* d_in, const int* in_sizes, int n_in,
                              void* d_out, int out_size, void* d_ws, size_t ws_size,
                              hipStream_t stream){
  const float* feat0  = (const float*)d_in[0];
  const float* feat1  = (const float*)d_in[1];
  const float* W0     = (const float*)d_in[2];
  const float* b0     = (const float*)d_in[3];
  const float* W1     = (const float*)d_in[4];
  const float* b1     = (const float*)d_in[5];
  const float* r_vec  = (const float*)d_in[6];
  const float* attn0  = (const float*)d_in[7];
  const float* attn1  = (const float*)d_in[8];
  const float* fc1_w  = (const float*)d_in[9];
  const float* fc1_b  = (const float*)d_in[10];
  const float* fc2_w  = (const float*)d_in[11];
  const float* fc_w   = (const float*)d_in[12];
  const float* fc_b   = (const float*)d_in[13];
  const int*   idx0   = (const int*)d_in[14];
  const int*   idx1   = (const int*)d_in[15];
  const int*   mpi[2] = { (const int*)d_in[16], (const int*)d_in[19] };
  const int*   mdst[2]= { (const int*)d_in[17], (const int*)d_in[20] };
  const int*   mtgt[2]= { (const int*)d_in[18], (const int*)d_in[21] };
  const float* attn[2]= { attn0, attn1 };

  float* ws      = (float*)d_ws;
  float* tf      = ws + OFF_TF;
  float* finals  = ws + OFF_FINALS;
  float* acc     = ws + OFF_ACC;
  float* beta    = ws + OFF_BETA;
  float* a_buf   = ws + OFF_A;
  unsigned* m_buf= (unsigned*)(ws + OFF_M);
  float* s_buf   = ws + OFF_S;
  float* u_buf   = ws + OFF_U;
  float* outp[2] = { ws + OFF_OUT0, ws + OFF_OUT1 };

  k_prep<<<1, 64, 0, stream>>>(r_vec, finals, acc, beta);
  k_transform<<<(NT0*64 + 255)/256, 256, 0, stream>>>(feat0, W0, b0, idx0, NT0, FD0, tf);
  k_transform<<<(NT1*64 + 255)/256, 256, 0, stream>>>(feat1, W1, b1, idx1, NT1, FD1, tf);

  for (int p = 0; p < 2; ++p){
    k_init<<<(NG*512 + 255)/256, 256, 0, stream>>>(m_buf, s_buf, u_buf);
    k_passA<<<(NE*32 + 255)/256, 256, 0, stream>>>(tf, mpi[p], mdst[p], finals + p*192,
                                                   attn[p], a_buf, m_buf);
    k_passB<<<(NE*32 + 255)/256, 256, 0, stream>>>(tf, mpi[p], mdst[p], finals + p*192,
                                                   a_buf, m_buf, s_buf, u_buf);
    k_out<<<(NB*512 + 255)/256, 256, 0, stream>>>(u_buf, s_buf, mtgt[p], outp[p]);
  }

  k_s1<<<256, 128, 0, stream>>>(outp[0], fc1_w, fc1_b, acc);
  k_s1<<<256, 128, 0, stream>>>(outp[1], fc1_w, fc1_b, acc + 128);
  k_beta<<<1, 64, 0, stream>>>(acc, fc2_w, beta);
  k_final<<<NB, 512, 0, stream>>>(outp[0], outp[1], beta, fc_w, fc_b, (float*)d_out);
}

// Round 2
// 1208.777 us; speedup vs baseline: 2.2414x; 2.2414x over previous
//
#include <hip/hip_runtime.h>
#include <math.h>

#define NNODES 100000
#define NT0 60000
#define NT1 40000
#define FD0 128
#define FD1 64
#define HID 64
#define HEADS 8
#define OUTD 16
#define AVEC 128
#define NE 250000
#define NG 8192
#define NB 8192

// workspace layout (float offsets)
#define OFF_TF      0ull          // 100000*64 = 6,400,000
#define OFF_FINALS  6400000ull    // 512
#define OFF_ACC     6400512ull    // 256
#define OFF_BETA    6400768ull    // 256
#define OFF_SORTED  6401024ull    // NE int4 = 1,000,000
#define OFF_COUNTS  7401024ull    // 8192 (ints)
#define OFF_CURS    7409216ull    // 8192 (ints)   -- contiguous with counts
#define OFF_OFFS    7417408ull    // 8256 (ints, 8193 used)
#define OFF_FT      7425664ull    // NG*512 = 4,194,304
#define OFF_OUT0    11619968ull   // NB*512 = 4,194,304
#define OFF_OUT1    15814272ull   // NB*512 = 4,194,304
// total = 20,008,576 floats = 80.0 MB (< 84.46 MB used last round)

// ---- prep: normalize r_vec, build finals for both metapaths, zero acc ----
__global__ void k_prep(const float* __restrict__ r_vec, float* __restrict__ finals,
                       float* __restrict__ acc, float* __restrict__ beta){
  int j = threadIdx.x;
  if (j < 32){
    const float2* rv = (const float2*)r_vec;
    float2 r0 = rv[j];        // relation 0, pair j
    float2 r1 = rv[32 + j];   // relation 1
    float n0 = rsqrtf(r0.x*r0.x + r0.y*r0.y);
    float n1 = rsqrtf(r1.x*r1.x + r1.y*r1.y);
    r0.x *= n0; r0.y *= n0; r1.x *= n1; r1.y *= n1;
    float2 rf1 = make_float2(r0.x, -r0.y);   // conj(r0)
    float2 rf3 = make_float2(r1.x, -r1.y);   // conj(r1)
    float2* F = (float2*)finals;  // [2][3][32] complex
    // metapath 0: etypes [0,1] -> rv_full idx 0,1: finals=[rf1*r0, rf1, 1]
    F[(0*3+2)*32 + j] = make_float2(1.f, 0.f);
    F[(0*3+1)*32 + j] = rf1;
    F[(0*3+0)*32 + j] = make_float2(rf1.x*r0.x - rf1.y*r0.y, rf1.x*r0.y + rf1.y*r0.x);
    // metapath 1: etypes [2,3] -> rv_full idx 2,3: finals=[rf3*r1, rf3, 1]
    F[(1*3+2)*32 + j] = make_float2(1.f, 0.f);
    F[(1*3+1)*32 + j] = rf3;
    F[(1*3+0)*32 + j] = make_float2(rf3.x*r1.x - rf3.y*r1.y, rf3.x*r1.y + rf3.y*r1.x);
  }
  for (int t = threadIdx.x; t < 256; t += 64) acc[t] = 0.f;
  if (threadIdx.x < 2) beta[threadIdx.x] = 0.f;
}

// ---- per-type linear into dense node table ----
__global__ void k_transform(const float* __restrict__ feat, const float* __restrict__ W,
                            const float* __restrict__ bias, const int* __restrict__ idx,
                            int n_nodes, int F, float* __restrict__ tf){
  int t = blockIdx.x*blockDim.x + threadIdx.x;
  int node = t >> 6; int d = t & 63;
  if (node >= n_nodes) return;
  const float4* f4 = (const float4*)(feat + (size_t)node * F);
  const float4* w4 = (const float4*)(W + (size_t)d * F);
  float s = bias[d];
  int nf4 = F >> 2;
  for (int f = 0; f < nf4; ++f){
    float4 a = f4[f], b = w4[f];
    s += a.x*b.x + a.y*b.y + a.z*b.z + a.w*b.w;
  }
  tf[(size_t)idx[node]*HID + d] = s;
}

// ---- zero int buffer ----
__global__ void k_zeroi(int* __restrict__ p, int n){
  int t = blockIdx.x*blockDim.x + threadIdx.x;
  if (t < n) p[t] = 0;
}

// ---- histogram of dst ----
__global__ void k_hist(const int* __restrict__ dst, int* __restrict__ counts){
  int e = blockIdx.x*blockDim.x + threadIdx.x;
  if (e < NE) atomicAdd(&counts[dst[e]], 1);
}

// ---- exclusive scan over 8192 counts (single block, 1024 threads) ----
__global__ __launch_bounds__(1024) void k_scan(const int* __restrict__ counts,
                                               int* __restrict__ offs){
  __shared__ int lds[1024];
  int t = threadIdx.x;
  int base = t*8;
  int v[8]; int sum = 0;
  #pragma unroll
  for (int i = 0; i < 8; ++i){ v[i] = counts[base+i]; sum += v[i]; }
  lds[t] = sum;
  __syncthreads();
  for (int off = 1; off < 1024; off <<= 1){
    int x = (t >= off) ? lds[t-off] : 0;
    __syncthreads();
    lds[t] += x;
    __syncthreads();
  }
  int excl = lds[t] - sum;
  #pragma unroll
  for (int i = 0; i < 8; ++i){ offs[base+i] = excl; excl += v[i]; }
  if (t == 1023) offs[NG] = excl;
}

// ---- scatter edges into dst-sorted order (node triples packed as int4) ----
__global__ void k_scatter(const int* __restrict__ mpi, const int* __restrict__ dst,
                          const int* __restrict__ offs, int* __restrict__ curs,
                          int4* __restrict__ sorted){
  int e = blockIdx.x*blockDim.x + threadIdx.x;
  if (e >= NE) return;
  int d = dst[e];
  int pos = offs[d] + atomicAdd(&curs[d], 1);
  sorted[pos] = make_int4(mpi[e*3], mpi[e*3+1], mpi[e*3+2], 0);
}

// ---- fused per-segment: h, logits, online softmax, weighted agg, normalize ----
__global__ __launch_bounds__(64) void k_seg(const float* __restrict__ tf,
                                            const int4* __restrict__ sorted,
                                            const int* __restrict__ offs,
                                            const float* __restrict__ finals_p,
                                            const float* __restrict__ attn,
                                            float* __restrict__ ft){
  int g = blockIdx.x;
  int lane = threadIdx.x;
  int hw = lane >> 5, j = lane & 31;
  int start = offs[g], end = offs[g+1];
  float2* ftw = (float2*)(ft + (size_t)g*512);
  if (start == end){
    #pragma unroll
    for (int kk = 0; kk < 4; ++kk){
      int k = hw*4 + kk;
      ftw[k*32 + j] = make_float2(0.f, 0.f);
    }
    return;
  }
  const float2* F2 = (const float2*)finals_p;
  float2 f0 = F2[j], f1 = F2[32 + j];
  float2 aw[8];
  const float2* at2 = (const float2*)attn;
  #pragma unroll
  for (int k = 0; k < 8; ++k) aw[k] = at2[k*32 + j];
  float m[8], s[8], ure[8], uim[8];
  #pragma unroll
  for (int k = 0; k < 8; ++k){ m[k] = -INFINITY; s[k] = 0.f; ure[k] = 0.f; uim[k] = 0.f; }
  const float2* tf2 = (const float2*)tf;
  for (int i = start + hw; i < end; i += 2){
    int4 nd = sorted[i];
    float2 v0 = tf2[(size_t)nd.x*32 + j];
    float2 v1 = tf2[(size_t)nd.y*32 + j];
    float2 v2 = tf2[(size_t)nd.z*32 + j];
    float hre = (v0.x*f0.x - v0.y*f0.y) + (v1.x*f1.x - v1.y*f1.y) + v2.x;
    float him = (v0.x*f0.y + v0.y*f0.x) + (v1.x*f1.y + v1.y*f1.x) + v2.y;
    hre *= (1.f/3.f); him *= (1.f/3.f);
    float p[8];
    #pragma unroll
    for (int k = 0; k < 8; ++k) p[k] = hre*aw[k].x + him*aw[k].y;
    #pragma unroll
    for (int mask = 1; mask < 32; mask <<= 1){
      #pragma unroll
      for (int k = 0; k < 8; ++k) p[k] += __shfl_xor(p[k], mask);
    }
    #pragma unroll
    for (int k = 0; k < 8; ++k){
      float a = p[k] > 0.f ? p[k] : 0.01f*p[k];    // leaky_relu
      float mn = fmaxf(m[k], a);
      float c = __expf(m[k] - mn);                 // 1.0 when max unchanged
      float e = __expf(a - mn);
      s[k]   = s[k]*c   + e;
      ure[k] = ure[k]*c + e*hre;
      uim[k] = uim[k]*c + e*him;
      m[k] = mn;
    }
  }
  // merge the two half-wave online states (lane j <-> lane j+32)
  #pragma unroll
  for (int k = 0; k < 8; ++k){
    float om  = __shfl_xor(m[k], 32);
    float os  = __shfl_xor(s[k], 32);
    float ore = __shfl_xor(ure[k], 32);
    float oim = __shfl_xor(uim[k], 32);
    float mn = fmaxf(m[k], om);
    float c  = __expf(m[k] - mn);   // half-wave 0 always non-empty -> mn finite
    float oc = __expf(om - mn);
    s[k]   = s[k]*c   + os*oc;
    ure[k] = ure[k]*c + ore*oc;
    uim[k] = uim[k]*c + oim*oc;
  }
  // normalize + write (half-wave 0 writes heads 0..3, half-wave 1 heads 4..7)
  #pragma unroll
  for (int kk = 0; kk < 4; ++kk){
    int k = hw*4 + kk;
    float inv = s[k] > 0.f ? 1.f/s[k] : 0.f;
    ftw[k*32 + j] = make_float2(ure[k]*inv, uim[k]*inv);
  }
}

// ---- gather targets + elu ----
__global__ void k_out(const float* __restrict__ ft, const int* __restrict__ target,
                      float* __restrict__ outp){
  int t = blockIdx.x*blockDim.x + threadIdx.x;
  if (t >= NB*512) return;
  int b = t >> 9, c = t & 511;
  float v = ft[(size_t)target[b]*512 + c];
  outp[t] = v > 0.f ? v : expm1f(v);   // elu
}

// ---- metapath-attention: accumulate mean of tanh(fc1 @ out + b) ----
__global__ void k_s1(const float* __restrict__ outp, const float* __restrict__ fc1_w,
                     const float* __restrict__ fc1_b, float* __restrict__ acc_p){
  __shared__ float lds[512];
  int t = threadIdx.x;  // 128
  float local = 0.f;
  for (int b = blockIdx.x; b < NB; b += gridDim.x){
    ((float4*)lds)[t] = ((const float4*)(outp + (size_t)b*512))[t];
    __syncthreads();
    float s = fc1_b[t];
    const float4* w = (const float4*)(fc1_w + (size_t)t*512);
    #pragma unroll 4
    for (int i = 0; i < 128; ++i){
      float4 a = ((float4*)lds)[i], ww = w[i];
      s += a.x*ww.x + a.y*ww.y + a.z*ww.z + a.w*ww.w;
    }
    local += tanhf(s);
    __syncthreads();
  }
  atomicAdd(&acc_p[t], local);
}

// ---- beta softmax over 2 metapaths ----
__global__ void k_beta(const float* __restrict__ acc, const float* __restrict__ fc2_w,
                       float* __restrict__ beta){
  int t = threadIdx.x;  // 64
  float s0 = acc[t]*fc2_w[t] + acc[t+64]*fc2_w[t+64];
  float s1 = acc[128+t]*fc2_w[t] + acc[192+t]*fc2_w[t+64];
  #pragma unroll
  for (int mask = 1; mask < 64; mask <<= 1){
    s0 += __shfl_xor(s0, mask, 64);
    s1 += __shfl_xor(s1, mask, 64);
  }
  if (t == 0){
    float z0 = s0 / (float)NB, z1 = s1 / (float)NB;
    float mz = fmaxf(z0, z1);
    float e0 = expf(z0 - mz), e1 = expf(z1 - mz);
    float inv = 1.f / (e0 + e1);
    beta[0] = e0*inv; beta[1] = e1*inv;
  }
}

// ---- hagg + logits ----
__global__ void k_final(const float* __restrict__ out0, const float* __restrict__ out1,
                        const float* __restrict__ beta, const float* __restrict__ fc_w,
                        const float* __restrict__ fc_b, float* __restrict__ d_out){
  __shared__ float lds[512];
  int b = blockIdx.x, t = threadIdx.x;  // 512 threads
  float b0 = beta[0], b1 = beta[1];
  float h = b0*out0[(size_t)b*512 + t] + b1*out1[(size_t)b*512 + t];
  lds[t] = h;
  d_out[(size_t)NB*OUTD + (size_t)b*512 + t] = h;
  __syncthreads();
  int o = t >> 5, j = t & 31;
  float s = 0.f;
  const float* w = fc_w + o*512;
  for (int d = j; d < 512; d += 32) s += lds[d]*w[d];
  #pragma unroll
  for (int mask = 1; mask < 32; mask <<= 1) s += __shfl_xor(s, mask, 32);
  if (j == 0) d_out[(size_t)b*OUTD + o] = s + fc_b[o];
}

extern "C" void kernel_launch(void* const* d_in, const int* in_sizes, int n_in,
                              void* d_out, int out_size, void* d_ws, size_t ws_size,
                              hipStream_t stream){
  const float* feat0  = (const float*)d_in[0];
  const float* feat1  = (const float*)d_in[1];
  const float* W0     = (const float*)d_in[2];
  const float* b0     = (const float*)d_in[3];
  const float* W1     = (const float*)d_in[4];
  const float* b1     = (const float*)d_in[5];
  const float* r_vec  = (const float*)d_in[6];
  const float* attn0  = (const float*)d_in[7];
  const float* attn1  = (const float*)d_in[8];
  const float* fc1_w  = (const float*)d_in[9];
  const float* fc1_b  = (const float*)d_in[10];
  const float* fc2_w  = (const float*)d_in[11];
  const float* fc_w   = (const float*)d_in[12];
  const float* fc_b   = (const float*)d_in[13];
  const int*   idx0   = (const int*)d_in[14];
  const int*   idx1   = (const int*)d_in[15];
  const int*   mpi[2] = { (const int*)d_in[16], (const int*)d_in[19] };
  const int*   mdst[2]= { (const int*)d_in[17], (const int*)d_in[20] };
  const int*   mtgt[2]= { (const int*)d_in[18], (const int*)d_in[21] };
  const float* attn[2]= { attn0, attn1 };

  float* ws      = (float*)d_ws;
  float* tf      = ws + OFF_TF;
  float* finals  = ws + OFF_FINALS;
  float* acc     = ws + OFF_ACC;
  float* beta    = ws + OFF_BETA;
  int4*  sorted  = (int4*)(ws + OFF_SORTED);
  int*   counts  = (int*)(ws + OFF_COUNTS);
  int*   curs    = (int*)(ws + OFF_CURS);
  int*   offs    = (int*)(ws + OFF_OFFS);
  float* ftb     = ws + OFF_FT;
  float* outp[2] = { ws + OFF_OUT0, ws + OFF_OUT1 };

  k_prep<<<1, 64, 0, stream>>>(r_vec, finals, acc, beta);
  k_transform<<<(NT0*64 + 255)/256, 256, 0, stream>>>(feat0, W0, b0, idx0, NT0, FD0, tf);
  k_transform<<<(NT1*64 + 255)/256, 256, 0, stream>>>(feat1, W1, b1, idx1, NT1, FD1, tf);

  for (int p = 0; p < 2; ++p){
    k_zeroi<<<64, 256, 0, stream>>>(counts, 2*NG);            // counts + cursors
    k_hist<<<(NE + 255)/256, 256, 0, stream>>>(mdst[p], counts);
    k_scan<<<1, 1024, 0, stream>>>(counts, offs);
    k_scatter<<<(NE + 255)/256, 256, 0, stream>>>(mpi[p], mdst[p], offs, curs, sorted);
    k_seg<<<NG, 64, 0, stream>>>(tf, sorted, offs, finals + p*192, attn[p], ftb);
    k_out<<<(NB*512 + 255)/256, 256, 0, stream>>>(ftb, mtgt[p], outp[p]);
  }

  k_s1<<<256, 128, 0, stream>>>(outp[0], fc1_w, fc1_b, acc);
  k_s1<<<256, 128, 0, stream>>>(outp[1], fc1_w, fc1_b, acc + 128);
  k_beta<<<1, 64, 0, stream>>>(acc, fc2_w, beta);
  k_final<<<NB, 512, 0, stream>>>(outp[0], outp[1], beta, fc_w, fc_b, (float*)d_out);
}

// Round 3
// 866.255 us; speedup vs baseline: 3.1276x; 1.3954x over previous
//
#include <hip/hip_runtime.h>
#include <math.h>

#define NNODES 100000
#define NT0 60000
#define NT1 40000
#define FD0 128
#define FD1 64
#define HID 64
#define HEADS 8
#define OUTD 16
#define AVEC 128
#define NE 250000
#define NG 8192
#define NB 8192

// workspace layout (float offsets)
#define OFF_TF      0ull          // 100000*64 = 6,400,000
#define OFF_FINALS  6400000ull    // 512
#define OFF_ACC     6400512ull    // 256
#define OFF_BETA    6400768ull    // 256
#define OFF_SORTED  6401024ull    // NE int4 = 1,000,000
#define OFF_COUNTS  7401024ull    // 8192 (ints)
#define OFF_CURS    7409216ull    // 8192 (ints)
#define OFF_OFFS    7417408ull    // 8256 (ints, 8193 used)
#define OFF_FT      7425664ull    // NG*512 = 4,194,304
#define OFF_OUT0    11619968ull   // NB*512 = 4,194,304
#define OFF_OUT1    15814272ull   // NB*512 = 4,194,304

// ---- prep: normalize r_vec, build finals for both metapaths, zero acc ----
__global__ void k_prep(const float* __restrict__ r_vec, float* __restrict__ finals,
                       float* __restrict__ acc, float* __restrict__ beta){
  int j = threadIdx.x;
  if (j < 32){
    const float2* rv = (const float2*)r_vec;
    float2 r0 = rv[j];
    float2 r1 = rv[32 + j];
    float n0 = rsqrtf(r0.x*r0.x + r0.y*r0.y);
    float n1 = rsqrtf(r1.x*r1.x + r1.y*r1.y);
    r0.x *= n0; r0.y *= n0; r1.x *= n1; r1.y *= n1;
    float2 rf1 = make_float2(r0.x, -r0.y);   // conj(r0)
    float2 rf3 = make_float2(r1.x, -r1.y);   // conj(r1)
    float2* F = (float2*)finals;  // [2][3][32] complex
    F[(0*3+2)*32 + j] = make_float2(1.f, 0.f);
    F[(0*3+1)*32 + j] = rf1;
    F[(0*3+0)*32 + j] = make_float2(rf1.x*r0.x - rf1.y*r0.y, rf1.x*r0.y + rf1.y*r0.x);
    F[(1*3+2)*32 + j] = make_float2(1.f, 0.f);
    F[(1*3+1)*32 + j] = rf3;
    F[(1*3+0)*32 + j] = make_float2(rf3.x*r1.x - rf3.y*r1.y, rf3.x*r1.y + rf3.y*r1.x);
  }
  for (int t = threadIdx.x; t < 256; t += 64) acc[t] = 0.f;
  if (threadIdx.x < 2) beta[threadIdx.x] = 0.f;
}

// ---- tiled per-type linear: tf[idx[m]] = feat[m] @ W.T + b ----
// block: 256 threads, tile 64 nodes x 64 dims, TK=32, 4x4 micro-tile
__global__ __launch_bounds__(256) void k_transform(const float* __restrict__ feat,
                                                   const float* __restrict__ W,
                                                   const float* __restrict__ bias,
                                                   const int* __restrict__ idx,
                                                   int n_nodes, int F,
                                                   float* __restrict__ tf){
  __shared__ float A[32][68];   // A[k][m]  (feat tile, transposed)
  __shared__ float Bs[32][68];  // B[k][d]  (W tile, transposed)
  int t = threadIdx.x;
  int tx = t & 15;        // node group (4 nodes)
  int ty = t >> 4;        // dim group  (4 dims)
  int m0 = blockIdx.x * 64;
  int Fq = F >> 2;

  float acc[4][4];
  #pragma unroll
  for (int i = 0; i < 4; ++i)
    #pragma unroll
    for (int j = 0; j < 4; ++j) acc[i][j] = 0.f;

  const float4* feat4 = (const float4*)feat;
  const float4* W4 = (const float4*)W;

  for (int k0 = 0; k0 < F; k0 += 32){
    // stage A: 64 nodes x 32 k = 512 float4, 2 per thread
    #pragma unroll
    for (int qq = 0; qq < 2; ++qq){
      int q = t + qq*256;
      int m = q >> 3, kq = q & 7;
      int gm = m0 + m; if (gm > n_nodes - 1) gm = n_nodes - 1;
      float4 v = feat4[(size_t)gm*Fq + (k0 >> 2) + kq];
      A[kq*4+0][m] = v.x; A[kq*4+1][m] = v.y; A[kq*4+2][m] = v.z; A[kq*4+3][m] = v.w;
    }
    // stage B: 64 dims x 32 k = 512 float4, 2 per thread
    #pragma unroll
    for (int qq = 0; qq < 2; ++qq){
      int q = t + qq*256;
      int d = q >> 3, kq = q & 7;
      float4 v = W4[(size_t)d*Fq + (k0 >> 2) + kq];
      Bs[kq*4+0][d] = v.x; Bs[kq*4+1][d] = v.y; Bs[kq*4+2][d] = v.z; Bs[kq*4+3][d] = v.w;
    }
    __syncthreads();
    #pragma unroll
    for (int kk = 0; kk < 32; ++kk){
      float4 a = *(const float4*)&A[kk][tx*4];
      float4 b = *(const float4*)&Bs[kk][ty*4];
      acc[0][0] += a.x*b.x; acc[0][1] += a.x*b.y; acc[0][2] += a.x*b.z; acc[0][3] += a.x*b.w;
      acc[1][0] += a.y*b.x; acc[1][1] += a.y*b.y; acc[1][2] += a.y*b.z; acc[1][3] += a.y*b.w;
      acc[2][0] += a.z*b.x; acc[2][1] += a.z*b.y; acc[2][2] += a.z*b.z; acc[2][3] += a.z*b.w;
      acc[3][0] += a.w*b.x; acc[3][1] += a.w*b.y; acc[3][2] += a.w*b.z; acc[3][3] += a.w*b.w;
    }
    __syncthreads();
  }

  float4 bv = *(const float4*)&bias[ty*4];
  #pragma unroll
  for (int i = 0; i < 4; ++i){
    int gm = m0 + tx*4 + i;
    if (gm < n_nodes){
      float4 o = make_float4(acc[i][0] + bv.x, acc[i][1] + bv.y,
                             acc[i][2] + bv.z, acc[i][3] + bv.w);
      *(float4*)&tf[(size_t)idx[gm]*HID + ty*4] = o;
    }
  }
}

// ---- zero int buffer ----
__global__ void k_zeroi(int* __restrict__ p, int n){
  int t = blockIdx.x*blockDim.x + threadIdx.x;
  if (t < n) p[t] = 0;
}

// ---- histogram of dst ----
__global__ void k_hist(const int* __restrict__ dst, int* __restrict__ counts){
  int e = blockIdx.x*blockDim.x + threadIdx.x;
  if (e < NE) atomicAdd(&counts[dst[e]], 1);
}

// ---- exclusive scan over 8192 counts (single block, 1024 threads) ----
__global__ __launch_bounds__(1024) void k_scan(const int* __restrict__ counts,
                                               int* __restrict__ offs){
  __shared__ int lds[1024];
  int t = threadIdx.x;
  int base = t*8;
  int v[8]; int sum = 0;
  #pragma unroll
  for (int i = 0; i < 8; ++i){ v[i] = counts[base+i]; sum += v[i]; }
  lds[t] = sum;
  __syncthreads();
  for (int off = 1; off < 1024; off <<= 1){
    int x = (t >= off) ? lds[t-off] : 0;
    __syncthreads();
    lds[t] += x;
    __syncthreads();
  }
  int excl = lds[t] - sum;
  #pragma unroll
  for (int i = 0; i < 8; ++i){ offs[base+i] = excl; excl += v[i]; }
  if (t == 1023) offs[NG] = excl;
}

// ---- scatter edges into dst-sorted order (node triples packed as int4) ----
__global__ void k_scatter(const int* __restrict__ mpi, const int* __restrict__ dst,
                          const int* __restrict__ offs, int* __restrict__ curs,
                          int4* __restrict__ sorted){
  int e = blockIdx.x*blockDim.x + threadIdx.x;
  if (e >= NE) return;
  int d = dst[e];
  int pos = offs[d] + atomicAdd(&curs[d], 1);
  sorted[pos] = make_int4(mpi[e*3], mpi[e*3+1], mpi[e*3+2], 0);
}

// ---- fused per-segment: h, logits, online softmax, weighted agg, normalize ----
__global__ __launch_bounds__(64) void k_seg(const float* __restrict__ tf,
                                            const int4* __restrict__ sorted,
                                            const int* __restrict__ offs,
                                            const float* __restrict__ finals_p,
                                            const float* __restrict__ attn,
                                            float* __restrict__ ft){
  int g = blockIdx.x;
  int lane = threadIdx.x;
  int hw = lane >> 5, j = lane & 31;
  int start = offs[g], end = offs[g+1];
  float2* ftw = (float2*)(ft + (size_t)g*512);
  if (start == end){
    #pragma unroll
    for (int kk = 0; kk < 4; ++kk){
      int k = hw*4 + kk;
      ftw[k*32 + j] = make_float2(0.f, 0.f);
    }
    return;
  }
  const float2* F2 = (const float2*)finals_p;
  float2 f0 = F2[j], f1 = F2[32 + j];
  float2 aw[8];
  const float2* at2 = (const float2*)attn;
  #pragma unroll
  for (int k = 0; k < 8; ++k) aw[k] = at2[k*32 + j];
  float m[8], s[8], ure[8], uim[8];
  #pragma unroll
  for (int k = 0; k < 8; ++k){ m[k] = -INFINITY; s[k] = 0.f; ure[k] = 0.f; uim[k] = 0.f; }
  const float2* tf2 = (const float2*)tf;
  for (int i = start + hw; i < end; i += 2){
    int4 nd = sorted[i];
    float2 v0 = tf2[(size_t)nd.x*32 + j];
    float2 v1 = tf2[(size_t)nd.y*32 + j];
    float2 v2 = tf2[(size_t)nd.z*32 + j];
    float hre = (v0.x*f0.x - v0.y*f0.y) + (v1.x*f1.x - v1.y*f1.y) + v2.x;
    float him = (v0.x*f0.y + v0.y*f0.x) + (v1.x*f1.y + v1.y*f1.x) + v2.y;
    hre *= (1.f/3.f); him *= (1.f/3.f);
    float p[8];
    #pragma unroll
    for (int k = 0; k < 8; ++k) p[k] = hre*aw[k].x + him*aw[k].y;
    #pragma unroll
    for (int mask = 1; mask < 32; mask <<= 1){
      #pragma unroll
      for (int k = 0; k < 8; ++k) p[k] += __shfl_xor(p[k], mask);
    }
    #pragma unroll
    for (int k = 0; k < 8; ++k){
      float a = p[k] > 0.f ? p[k] : 0.01f*p[k];    // leaky_relu
      float mn = fmaxf(m[k], a);
      float c = __expf(m[k] - mn);
      float e = __expf(a - mn);
      s[k]   = s[k]*c   + e;
      ure[k] = ure[k]*c + e*hre;
      uim[k] = uim[k]*c + e*him;
      m[k] = mn;
    }
  }
  // merge the two half-wave online states
  #pragma unroll
  for (int k = 0; k < 8; ++k){
    float om  = __shfl_xor(m[k], 32);
    float os  = __shfl_xor(s[k], 32);
    float ore = __shfl_xor(ure[k], 32);
    float oim = __shfl_xor(uim[k], 32);
    float mn = fmaxf(m[k], om);
    float c  = __expf(m[k] - mn);
    float oc = __expf(om - mn);
    s[k]   = s[k]*c   + os*oc;
    ure[k] = ure[k]*c + ore*oc;
    uim[k] = uim[k]*c + oim*oc;
  }
  #pragma unroll
  for (int kk = 0; kk < 4; ++kk){
    int k = hw*4 + kk;
    float inv = s[k] > 0.f ? 1.f/s[k] : 0.f;
    ftw[k*32 + j] = make_float2(ure[k]*inv, uim[k]*inv);
  }
}

// ---- gather targets + elu ----
__global__ void k_out(const float* __restrict__ ft, const int* __restrict__ target,
                      float* __restrict__ outp){
  int t = blockIdx.x*blockDim.x + threadIdx.x;
  if (t >= NB*512) return;
  int b = t >> 9, c = t & 511;
  float v = ft[(size_t)target[b]*512 + c];
  outp[t] = v > 0.f ? v : expm1f(v);   // elu
}

// ---- metapath-attention: accumulate mean of tanh(fc1 @ out + b) ----
__global__ void k_s1(const float* __restrict__ outp, const float* __restrict__ fc1_w,
                     const float* __restrict__ fc1_b, float* __restrict__ acc_p){
  __shared__ float lds[512];
  int t = threadIdx.x;  // 128
  float local = 0.f;
  for (int b = blockIdx.x; b < NB; b += gridDim.x){
    ((float4*)lds)[t] = ((const float4*)(outp + (size_t)b*512))[t];
    __syncthreads();
    float s = fc1_b[t];
    const float4* w = (const float4*)(fc1_w + (size_t)t*512);
    #pragma unroll 4
    for (int i = 0; i < 128; ++i){
      float4 a = ((float4*)lds)[i], ww = w[i];
      s += a.x*ww.x + a.y*ww.y + a.z*ww.z + a.w*ww.w;
    }
    local += tanhf(s);
    __syncthreads();
  }
  atomicAdd(&acc_p[t], local);
}

// ---- beta softmax over 2 metapaths ----
__global__ void k_beta(const float* __restrict__ acc, const float* __restrict__ fc2_w,
                       float* __restrict__ beta){
  int t = threadIdx.x;  // 64
  float s0 = acc[t]*fc2_w[t] + acc[t+64]*fc2_w[t+64];
  float s1 = acc[128+t]*fc2_w[t] + acc[192+t]*fc2_w[t+64];
  #pragma unroll
  for (int mask = 1; mask < 64; mask <<= 1){
    s0 += __shfl_xor(s0, mask, 64);
    s1 += __shfl_xor(s1, mask, 64);
  }
  if (t == 0){
    float z0 = s0 / (float)NB, z1 = s1 / (float)NB;
    float mz = fmaxf(z0, z1);
    float e0 = expf(z0 - mz), e1 = expf(z1 - mz);
    float inv = 1.f / (e0 + e1);
    beta[0] = e0*inv; beta[1] = e1*inv;
  }
}

// ---- hagg + logits ----
__global__ void k_final(const float* __restrict__ out0, const float* __restrict__ out1,
                        const float* __restrict__ beta, const float* __restrict__ fc_w,
                        const float* __restrict__ fc_b, float* __restrict__ d_out){
  __shared__ float lds[512];
  int b = blockIdx.x, t = threadIdx.x;  // 512 threads
  float b0 = beta[0], b1 = beta[1];
  float h = b0*out0[(size_t)b*512 + t] + b1*out1[(size_t)b*512 + t];
  lds[t] = h;
  d_out[(size_t)NB*OUTD + (size_t)b*512 + t] = h;
  __syncthreads();
  int o = t >> 5, j = t & 31;
  float s = 0.f;
  const float* w = fc_w + o*512;
  for (int d = j; d < 512; d += 32) s += lds[d]*w[d];
  #pragma unroll
  for (int mask = 1; mask < 32; mask <<= 1) s += __shfl_xor(s, mask, 32);
  if (j == 0) d_out[(size_t)b*OUTD + o] = s + fc_b[o];
}

extern "C" void kernel_launch(void* const* d_in, const int* in_sizes, int n_in,
                              void* d_out, int out_size, void* d_ws, size_t ws_size,
                              hipStream_t stream){
  const float* feat0  = (const float*)d_in[0];
  const float* feat1  = (const float*)d_in[1];
  const float* W0     = (const float*)d_in[2];
  const float* b0     = (const float*)d_in[3];
  const float* W1     = (const float*)d_in[4];
  const float* b1     = (const float*)d_in[5];
  const float* r_vec  = (const float*)d_in[6];
  const float* attn0  = (const float*)d_in[7];
  const float* attn1  = (const float*)d_in[8];
  const float* fc1_w  = (const float*)d_in[9];
  const float* fc1_b  = (const float*)d_in[10];
  const float* fc2_w  = (const float*)d_in[11];
  const float* fc_w   = (const float*)d_in[12];
  const float* fc_b   = (const float*)d_in[13];
  const int*   idx0   = (const int*)d_in[14];
  const int*   idx1   = (const int*)d_in[15];
  const int*   mpi[2] = { (const int*)d_in[16], (const int*)d_in[19] };
  const int*   mdst[2]= { (const int*)d_in[17], (const int*)d_in[20] };
  const int*   mtgt[2]= { (const int*)d_in[18], (const int*)d_in[21] };
  const float* attn[2]= { attn0, attn1 };

  float* ws      = (float*)d_ws;
  float* tf      = ws + OFF_TF;
  float* finals  = ws + OFF_FINALS;
  float* acc     = ws + OFF_ACC;
  float* beta    = ws + OFF_BETA;
  int4*  sorted  = (int4*)(ws + OFF_SORTED);
  int*   counts  = (int*)(ws + OFF_COUNTS);
  int*   curs    = (int*)(ws + OFF_CURS);
  int*   offs    = (int*)(ws + OFF_OFFS);
  float* ftb     = ws + OFF_FT;
  float* outp[2] = { ws + OFF_OUT0, ws + OFF_OUT1 };

  k_prep<<<1, 64, 0, stream>>>(r_vec, finals, acc, beta);
  k_transform<<<(NT0 + 63)/64, 256, 0, stream>>>(feat0, W0, b0, idx0, NT0, FD0, tf);
  k_transform<<<(NT1 + 63)/64, 256, 0, stream>>>(feat1, W1, b1, idx1, NT1, FD1, tf);

  for (int p = 0; p < 2; ++p){
    k_zeroi<<<64, 256, 0, stream>>>(counts, 2*NG);            // counts + cursors
    k_hist<<<(NE + 255)/256, 256, 0, stream>>>(mdst[p], counts);
    k_scan<<<1, 1024, 0, stream>>>(counts, offs);
    k_scatter<<<(NE + 255)/256, 256, 0, stream>>>(mpi[p], mdst[p], offs, curs, sorted);
    k_seg<<<NG, 64, 0, stream>>>(tf, sorted, offs, finals + p*192, attn[p], ftb);
    k_out<<<(NB*512 + 255)/256, 256, 0, stream>>>(ftb, mtgt[p], outp[p]);
  }

  k_s1<<<256, 128, 0, stream>>>(outp[0], fc1_w, fc1_b, acc);
  k_s1<<<256, 128, 0, stream>>>(outp[1], fc1_w, fc1_b, acc + 128);
  k_beta<<<1, 64, 0, stream>>>(acc, fc2_w, beta);
  k_final<<<NB, 512, 0, stream>>>(outp[0], outp[1], beta, fc_w, fc_b, (float*)d_out);
}

// Round 4
// 401.699 us; speedup vs baseline: 6.7446x; 2.1565x over previous
//
#include <hip/hip_runtime.h>
#include <math.h>

#define NNODES 100000
#define NT0 60000
#define NT1 40000
#define FD0 128
#define FD1 64
#define HID 64
#define HEADS 8
#define OUTD 16
#define AVEC 128
#define NE 250000
#define NG 8192
#define NB 8192

// workspace layout (float offsets)
#define OFF_TF      0ull          // 100000*64 = 6,400,000
#define OFF_FINALS  6400000ull    // 512
#define OFF_ACC     6400512ull    // 256
#define OFF_BETA    6400768ull    // 256
#define OFF_SORTED  6401024ull    // NE int4 = 1,000,000
#define OFF_COUNTS  7401024ull    // 8192 (ints)
#define OFF_CURS    7409216ull    // 8192 (ints)
#define OFF_OFFS    7417408ull    // 8256 (ints, 8193 used)
#define OFF_FT0     7425664ull    // NG*512 = 4,194,304
#define OFF_FT1     11619968ull   // NG*512 = 4,194,304
// total = 15,814,272 floats = 63.3 MB

// ---- prep: normalize r_vec, build finals for both metapaths, zero acc ----
__global__ void k_prep(const float* __restrict__ r_vec, float* __restrict__ finals,
                       float* __restrict__ acc, float* __restrict__ beta){
  int j = threadIdx.x;
  if (j < 32){
    const float2* rv = (const float2*)r_vec;
    float2 r0 = rv[j];
    float2 r1 = rv[32 + j];
    float n0 = rsqrtf(r0.x*r0.x + r0.y*r0.y);
    float n1 = rsqrtf(r1.x*r1.x + r1.y*r1.y);
    r0.x *= n0; r0.y *= n0; r1.x *= n1; r1.y *= n1;
    float2 rf1 = make_float2(r0.x, -r0.y);   // conj(r0)
    float2 rf3 = make_float2(r1.x, -r1.y);   // conj(r1)
    float2* F = (float2*)finals;  // [2][3][32] complex
    F[(0*3+2)*32 + j] = make_float2(1.f, 0.f);
    F[(0*3+1)*32 + j] = rf1;
    F[(0*3+0)*32 + j] = make_float2(rf1.x*r0.x - rf1.y*r0.y, rf1.x*r0.y + rf1.y*r0.x);
    F[(1*3+2)*32 + j] = make_float2(1.f, 0.f);
    F[(1*3+1)*32 + j] = rf3;
    F[(1*3+0)*32 + j] = make_float2(rf3.x*r1.x - rf3.y*r1.y, rf3.x*r1.y + rf3.y*r1.x);
  }
  for (int t = threadIdx.x; t < 256; t += 64) acc[t] = 0.f;
  if (threadIdx.x < 2) beta[threadIdx.x] = 0.f;
}

// ---- tiled per-type linear: tf[idx[m]] = feat[m] @ W.T + b ----
__global__ __launch_bounds__(256) void k_transform(const float* __restrict__ feat,
                                                   const float* __restrict__ W,
                                                   const float* __restrict__ bias,
                                                   const int* __restrict__ idx,
                                                   int n_nodes, int F,
                                                   float* __restrict__ tf){
  __shared__ float A[32][68];   // A[k][m]
  __shared__ float Bs[32][68];  // B[k][d]
  int t = threadIdx.x;
  int tx = t & 15;
  int ty = t >> 4;
  int m0 = blockIdx.x * 64;
  int Fq = F >> 2;

  float acc[4][4];
  #pragma unroll
  for (int i = 0; i < 4; ++i)
    #pragma unroll
    for (int j = 0; j < 4; ++j) acc[i][j] = 0.f;

  const float4* feat4 = (const float4*)feat;
  const float4* W4 = (const float4*)W;

  for (int k0 = 0; k0 < F; k0 += 32){
    #pragma unroll
    for (int qq = 0; qq < 2; ++qq){
      int q = t + qq*256;
      int m = q >> 3, kq = q & 7;
      int gm = m0 + m; if (gm > n_nodes - 1) gm = n_nodes - 1;
      float4 v = feat4[(size_t)gm*Fq + (k0 >> 2) + kq];
      A[kq*4+0][m] = v.x; A[kq*4+1][m] = v.y; A[kq*4+2][m] = v.z; A[kq*4+3][m] = v.w;
    }
    #pragma unroll
    for (int qq = 0; qq < 2; ++qq){
      int q = t + qq*256;
      int d = q >> 3, kq = q & 7;
      float4 v = W4[(size_t)d*Fq + (k0 >> 2) + kq];
      Bs[kq*4+0][d] = v.x; Bs[kq*4+1][d] = v.y; Bs[kq*4+2][d] = v.z; Bs[kq*4+3][d] = v.w;
    }
    __syncthreads();
    #pragma unroll
    for (int kk = 0; kk < 32; ++kk){
      float4 a = *(const float4*)&A[kk][tx*4];
      float4 b = *(const float4*)&Bs[kk][ty*4];
      acc[0][0] += a.x*b.x; acc[0][1] += a.x*b.y; acc[0][2] += a.x*b.z; acc[0][3] += a.x*b.w;
      acc[1][0] += a.y*b.x; acc[1][1] += a.y*b.y; acc[1][2] += a.y*b.z; acc[1][3] += a.y*b.w;
      acc[2][0] += a.z*b.x; acc[2][1] += a.z*b.y; acc[2][2] += a.z*b.z; acc[2][3] += a.z*b.w;
      acc[3][0] += a.w*b.x; acc[3][1] += a.w*b.y; acc[3][2] += a.w*b.z; acc[3][3] += a.w*b.w;
    }
    __syncthreads();
  }

  float4 bv = *(const float4*)&bias[ty*4];
  #pragma unroll
  for (int i = 0; i < 4; ++i){
    int gm = m0 + tx*4 + i;
    if (gm < n_nodes){
      float4 o = make_float4(acc[i][0] + bv.x, acc[i][1] + bv.y,
                             acc[i][2] + bv.z, acc[i][3] + bv.w);
      *(float4*)&tf[(size_t)idx[gm]*HID + ty*4] = o;
    }
  }
}

// ---- zero int buffer ----
__global__ void k_zeroi(int* __restrict__ p, int n){
  int t = blockIdx.x*blockDim.x + threadIdx.x;
  if (t < n) p[t] = 0;
}

// ---- histogram of dst ----
__global__ void k_hist(const int* __restrict__ dst, int* __restrict__ counts){
  int e = blockIdx.x*blockDim.x + threadIdx.x;
  if (e < NE) atomicAdd(&counts[dst[e]], 1);
}

// ---- exclusive scan over 8192 counts ----
__global__ __launch_bounds__(1024) void k_scan(const int* __restrict__ counts,
                                               int* __restrict__ offs){
  __shared__ int lds[1024];
  int t = threadIdx.x;
  int base = t*8;
  int v[8]; int sum = 0;
  #pragma unroll
  for (int i = 0; i < 8; ++i){ v[i] = counts[base+i]; sum += v[i]; }
  lds[t] = sum;
  __syncthreads();
  for (int off = 1; off < 1024; off <<= 1){
    int x = (t >= off) ? lds[t-off] : 0;
    __syncthreads();
    lds[t] += x;
    __syncthreads();
  }
  int excl = lds[t] - sum;
  #pragma unroll
  for (int i = 0; i < 8; ++i){ offs[base+i] = excl; excl += v[i]; }
  if (t == 1023) offs[NG] = excl;
}

// ---- scatter edges into dst-sorted order ----
__global__ void k_scatter(const int* __restrict__ mpi, const int* __restrict__ dst,
                          const int* __restrict__ offs, int* __restrict__ curs,
                          int4* __restrict__ sorted){
  int e = blockIdx.x*blockDim.x + threadIdx.x;
  if (e >= NE) return;
  int d = dst[e];
  int pos = offs[d] + atomicAdd(&curs[d], 1);
  sorted[pos] = make_int4(mpi[e*3], mpi[e*3+1], mpi[e*3+2], 0);
}

// ---- fused per-segment: h, logits, online softmax, weighted agg, normalize ----
__global__ __launch_bounds__(64) void k_seg(const float* __restrict__ tf,
                                            const int4* __restrict__ sorted,
                                            const int* __restrict__ offs,
                                            const float* __restrict__ finals_p,
                                            const float* __restrict__ attn,
                                            float* __restrict__ ft){
  int g = blockIdx.x;
  int lane = threadIdx.x;
  int hw = lane >> 5, j = lane & 31;
  int start = offs[g], end = offs[g+1];
  float2* ftw = (float2*)(ft + (size_t)g*512);
  if (start == end){
    #pragma unroll
    for (int kk = 0; kk < 4; ++kk){
      int k = hw*4 + kk;
      ftw[k*32 + j] = make_float2(0.f, 0.f);
    }
    return;
  }
  const float2* F2 = (const float2*)finals_p;
  float2 f0 = F2[j], f1 = F2[32 + j];
  float2 aw[8];
  const float2* at2 = (const float2*)attn;
  #pragma unroll
  for (int k = 0; k < 8; ++k) aw[k] = at2[k*32 + j];
  float m[8], s[8], ure[8], uim[8];
  #pragma unroll
  for (int k = 0; k < 8; ++k){ m[k] = -INFINITY; s[k] = 0.f; ure[k] = 0.f; uim[k] = 0.f; }
  const float2* tf2 = (const float2*)tf;
  for (int i = start + hw; i < end; i += 2){
    int4 nd = sorted[i];
    float2 v0 = tf2[(size_t)nd.x*32 + j];
    float2 v1 = tf2[(size_t)nd.y*32 + j];
    float2 v2 = tf2[(size_t)nd.z*32 + j];
    float hre = (v0.x*f0.x - v0.y*f0.y) + (v1.x*f1.x - v1.y*f1.y) + v2.x;
    float him = (v0.x*f0.y + v0.y*f0.x) + (v1.x*f1.y + v1.y*f1.x) + v2.y;
    hre *= (1.f/3.f); him *= (1.f/3.f);
    float p[8];
    #pragma unroll
    for (int k = 0; k < 8; ++k) p[k] = hre*aw[k].x + him*aw[k].y;
    #pragma unroll
    for (int mask = 1; mask < 32; mask <<= 1){
      #pragma unroll
      for (int k = 0; k < 8; ++k) p[k] += __shfl_xor(p[k], mask);
    }
    #pragma unroll
    for (int k = 0; k < 8; ++k){
      float a = p[k] > 0.f ? p[k] : 0.01f*p[k];    // leaky_relu
      float mn = fmaxf(m[k], a);
      float c = __expf(m[k] - mn);
      float e = __expf(a - mn);
      s[k]   = s[k]*c   + e;
      ure[k] = ure[k]*c + e*hre;
      uim[k] = uim[k]*c + e*him;
      m[k] = mn;
    }
  }
  #pragma unroll
  for (int k = 0; k < 8; ++k){
    float om  = __shfl_xor(m[k], 32);
    float os  = __shfl_xor(s[k], 32);
    float ore = __shfl_xor(ure[k], 32);
    float oim = __shfl_xor(uim[k], 32);
    float mn = fmaxf(m[k], om);
    float c  = __expf(m[k] - mn);
    float oc = __expf(om - mn);
    s[k]   = s[k]*c   + os*oc;
    ure[k] = ure[k]*c + ore*oc;
    uim[k] = uim[k]*c + oim*oc;
  }
  #pragma unroll
  for (int kk = 0; kk < 4; ++kk){
    int k = hw*4 + kk;
    float inv = s[k] > 0.f ? 1.f/s[k] : 0.f;
    ftw[k*32 + j] = make_float2(ure[k]*inv, uim[k]*inv);
  }
}

// ---- fused s1 GEMM for both metapaths: acc[p][dim] += sum_b tanh(elu(ft[tgt[b]]) @ fc1_w.T + b)[dim]
// grid: 128 bblk x 2 dblk x 2 p = 512 blocks, 256 threads
__global__ __launch_bounds__(256) void k_s1g(const float* __restrict__ ft0,
                                             const float* __restrict__ ft1,
                                             const int* __restrict__ tgt0,
                                             const int* __restrict__ tgt1,
                                             const float* __restrict__ fc1_w,
                                             const float* __restrict__ fc1_b,
                                             float* __restrict__ acc_p){
  int bid = blockIdx.x;
  int bb = bid & 127;
  int db = (bid >> 7) & 1;
  int p  = bid >> 8;
  const float* ft = p ? ft1 : ft0;
  const int* tgt  = p ? tgt1 : tgt0;

  __shared__ float A[32][68];
  __shared__ float Bs[32][68];
  __shared__ int   tl[64];
  __shared__ float red[64][16];

  int t = threadIdx.x;
  int tx = t & 15, ty = t >> 4;
  if (t < 64) tl[t] = tgt[bb*64 + t];
  __syncthreads();

  float acc[4][4];
  #pragma unroll
  for (int i = 0; i < 4; ++i)
    #pragma unroll
    for (int j = 0; j < 4; ++j) acc[i][j] = 0.f;

  const float4* W4 = (const float4*)fc1_w;   // [128 rows][128 float4]

  for (int k0 = 0; k0 < 512; k0 += 32){
    #pragma unroll
    for (int qq = 0; qq < 2; ++qq){
      int q = t + qq*256;
      int m = q >> 3, kq = q & 7;
      const float4* row = (const float4*)(ft + (size_t)tl[m]*512);
      float4 v = row[(k0 >> 2) + kq];
      v.x = v.x > 0.f ? v.x : expm1f(v.x);
      v.y = v.y > 0.f ? v.y : expm1f(v.y);
      v.z = v.z > 0.f ? v.z : expm1f(v.z);
      v.w = v.w > 0.f ? v.w : expm1f(v.w);
      A[kq*4+0][m] = v.x; A[kq*4+1][m] = v.y; A[kq*4+2][m] = v.z; A[kq*4+3][m] = v.w;
    }
    #pragma unroll
    for (int qq = 0; qq < 2; ++qq){
      int q = t + qq*256;
      int d = q >> 3, kq = q & 7;
      float4 v = W4[(size_t)(db*64 + d)*128 + (k0 >> 2) + kq];
      Bs[kq*4+0][d] = v.x; Bs[kq*4+1][d] = v.y; Bs[kq*4+2][d] = v.z; Bs[kq*4+3][d] = v.w;
    }
    __syncthreads();
    #pragma unroll
    for (int kk = 0; kk < 32; ++kk){
      float4 a = *(const float4*)&A[kk][tx*4];
      float4 b = *(const float4*)&Bs[kk][ty*4];
      acc[0][0] += a.x*b.x; acc[0][1] += a.x*b.y; acc[0][2] += a.x*b.z; acc[0][3] += a.x*b.w;
      acc[1][0] += a.y*b.x; acc[1][1] += a.y*b.y; acc[1][2] += a.y*b.z; acc[1][3] += a.y*b.w;
      acc[2][0] += a.z*b.x; acc[2][1] += a.z*b.y; acc[2][2] += a.z*b.z; acc[2][3] += a.z*b.w;
      acc[3][0] += a.w*b.x; acc[3][1] += a.w*b.y; acc[3][2] += a.w*b.z; acc[3][3] += a.w*b.w;
    }
    __syncthreads();
  }

  float4 bv = *(const float4*)&fc1_b[db*64 + ty*4];
  float cs0 = 0.f, cs1 = 0.f, cs2 = 0.f, cs3 = 0.f;
  #pragma unroll
  for (int i = 0; i < 4; ++i){
    cs0 += tanhf(acc[i][0] + bv.x);
    cs1 += tanhf(acc[i][1] + bv.y);
    cs2 += tanhf(acc[i][2] + bv.z);
    cs3 += tanhf(acc[i][3] + bv.w);
  }
  red[ty*4+0][tx] = cs0;
  red[ty*4+1][tx] = cs1;
  red[ty*4+2][tx] = cs2;
  red[ty*4+3][tx] = cs3;
  __syncthreads();
  if (t < 64){
    float s = 0.f;
    #pragma unroll
    for (int x = 0; x < 16; ++x) s += red[t][x];
    atomicAdd(&acc_p[p*128 + db*64 + t], s);
  }
}

// ---- beta softmax over 2 metapaths ----
__global__ void k_beta(const float* __restrict__ acc, const float* __restrict__ fc2_w,
                       float* __restrict__ beta){
  int t = threadIdx.x;  // 64
  float s0 = acc[t]*fc2_w[t] + acc[t+64]*fc2_w[t+64];
  float s1 = acc[128+t]*fc2_w[t] + acc[192+t]*fc2_w[t+64];
  #pragma unroll
  for (int mask = 1; mask < 64; mask <<= 1){
    s0 += __shfl_xor(s0, mask, 64);
    s1 += __shfl_xor(s1, mask, 64);
  }
  if (t == 0){
    float z0 = s0 / (float)NB, z1 = s1 / (float)NB;
    float mz = fmaxf(z0, z1);
    float e0 = expf(z0 - mz), e1 = expf(z1 - mz);
    float inv = 1.f / (e0 + e1);
    beta[0] = e0*inv; beta[1] = e1*inv;
  }
}

// ---- hagg + logits (gather + elu fused) ----
__global__ void k_final(const float* __restrict__ ft0, const float* __restrict__ ft1,
                        const int* __restrict__ tgt0, const int* __restrict__ tgt1,
                        const float* __restrict__ beta, const float* __restrict__ fc_w,
                        const float* __restrict__ fc_b, float* __restrict__ d_out){
  __shared__ float lds[512];
  int b = blockIdx.x, t = threadIdx.x;  // 512 threads
  float b0 = beta[0], b1 = beta[1];
  int g0 = tgt0[b], g1 = tgt1[b];
  float v0 = ft0[(size_t)g0*512 + t]; v0 = v0 > 0.f ? v0 : expm1f(v0);
  float v1 = ft1[(size_t)g1*512 + t]; v1 = v1 > 0.f ? v1 : expm1f(v1);
  float h = b0*v0 + b1*v1;
  lds[t] = h;
  d_out[(size_t)NB*OUTD + (size_t)b*512 + t] = h;
  __syncthreads();
  int o = t >> 5, j = t & 31;
  float s = 0.f;
  const float* w = fc_w + o*512;
  for (int d = j; d < 512; d += 32) s += lds[d]*w[d];
  #pragma unroll
  for (int mask = 1; mask < 32; mask <<= 1) s += __shfl_xor(s, mask, 32);
  if (j == 0) d_out[(size_t)b*OUTD + o] = s + fc_b[o];
}

extern "C" void kernel_launch(void* const* d_in, const int* in_sizes, int n_in,
                              void* d_out, int out_size, void* d_ws, size_t ws_size,
                              hipStream_t stream){
  const float* feat0  = (const float*)d_in[0];
  const float* feat1  = (const float*)d_in[1];
  const float* W0     = (const float*)d_in[2];
  const float* b0     = (const float*)d_in[3];
  const float* W1     = (const float*)d_in[4];
  const float* b1     = (const float*)d_in[5];
  const float* r_vec  = (const float*)d_in[6];
  const float* attn0  = (const float*)d_in[7];
  const float* attn1  = (const float*)d_in[8];
  const float* fc1_w  = (const float*)d_in[9];
  const float* fc1_b  = (const float*)d_in[10];
  const float* fc2_w  = (const float*)d_in[11];
  const float* fc_w   = (const float*)d_in[12];
  const float* fc_b   = (const float*)d_in[13];
  const int*   idx0   = (const int*)d_in[14];
  const int*   idx1   = (const int*)d_in[15];
  const int*   mpi[2] = { (const int*)d_in[16], (const int*)d_in[19] };
  const int*   mdst[2]= { (const int*)d_in[17], (const int*)d_in[20] };
  const int*   mtgt[2]= { (const int*)d_in[18], (const int*)d_in[21] };
  const float* attn[2]= { attn0, attn1 };

  float* ws      = (float*)d_ws;
  float* tf      = ws + OFF_TF;
  float* finals  = ws + OFF_FINALS;
  float* acc     = ws + OFF_ACC;
  float* beta    = ws + OFF_BETA;
  int4*  sorted  = (int4*)(ws + OFF_SORTED);
  int*   counts  = (int*)(ws + OFF_COUNTS);
  int*   curs    = (int*)(ws + OFF_CURS);
  int*   offs    = (int*)(ws + OFF_OFFS);
  float* ftp[2]  = { ws + OFF_FT0, ws + OFF_FT1 };

  k_prep<<<1, 64, 0, stream>>>(r_vec, finals, acc, beta);
  k_transform<<<(NT0 + 63)/64, 256, 0, stream>>>(feat0, W0, b0, idx0, NT0, FD0, tf);
  k_transform<<<(NT1 + 63)/64, 256, 0, stream>>>(feat1, W1, b1, idx1, NT1, FD1, tf);

  for (int p = 0; p < 2; ++p){
    k_zeroi<<<64, 256, 0, stream>>>(counts, 2*NG);
    k_hist<<<(NE + 255)/256, 256, 0, stream>>>(mdst[p], counts);
    k_scan<<<1, 1024, 0, stream>>>(counts, offs);
    k_scatter<<<(NE + 255)/256, 256, 0, stream>>>(mpi[p], mdst[p], offs, curs, sorted);
    k_seg<<<NG, 64, 0, stream>>>(tf, sorted, offs, finals + p*192, attn[p], ftp[p]);
  }

  k_s1g<<<512, 256, 0, stream>>>(ftp[0], ftp[1], mtgt[0], mtgt[1], fc1_w, fc1_b, acc);
  k_beta<<<1, 64, 0, stream>>>(acc, fc2_w, beta);
  k_final<<<NB, 512, 0, stream>>>(ftp[0], ftp[1], mtgt[0], mtgt[1], beta, fc_w, fc_b,
                                  (float*)d_out);
}

// Round 5
// 294.477 us; speedup vs baseline: 9.2004x; 1.3641x over previous
//
#include <hip/hip_runtime.h>
#include <hip/hip_fp16.h>
#include <math.h>

#define NNODES 100000
#define NT0 60000
#define NT1 40000
#define FD0 128
#define FD1 64
#define HID 64
#define HEADS 8
#define OUTD 16
#define AVEC 128
#define NE 250000
#define NG 8192
#define NB 8192

// workspace layout (float offsets)
#define OFF_TF      0ull          // 6,400,000
#define OFF_FINALS  6400000ull    // 512   ([pi][pair] float2, pi=p*3+i)
#define OFF_A       6400512ull    // 3,072 (A[pi][k][d])
#define OFF_ACC     6403584ull    // 256
#define OFF_BETA    6403840ull    // 256
#define OFF_P       6404096ull    // 2,400,000 floats = 4,800,000 halves (P[p][n][24])
#define OFF_SORTED  8804096ull    // 2,000,000 (500,000 int4; byte off divisible by 16)
#define OFF_COUNTS  10804096ull   // 16,384
#define OFF_CURS    10820480ull   // 16,384
#define OFF_OFFS    10836864ull   // 16,640 (16,385 used)
#define OFF_FT      10853504ull   // 2*NG*512 = 8,388,608
// total = 19,242,112 floats = 77.0 MB

// ---- prep: finals + logit-projection matrices A, zero acc ----
__global__ __launch_bounds__(256) void k_prep(const float* __restrict__ r_vec,
                       const float* __restrict__ attn0, const float* __restrict__ attn1,
                       float* __restrict__ finals, float* __restrict__ A,
                       float* __restrict__ acc, float* __restrict__ beta){
  __shared__ float2 fl[192];   // [pi][pair]
  int t = threadIdx.x;
  if (t < 32){
    int j = t;
    const float2* rv = (const float2*)r_vec;
    float2 r0 = rv[j];
    float2 r1 = rv[32 + j];
    float n0 = rsqrtf(r0.x*r0.x + r0.y*r0.y);
    float n1 = rsqrtf(r1.x*r1.x + r1.y*r1.y);
    r0.x *= n0; r0.y *= n0; r1.x *= n1; r1.y *= n1;
    float2 rf1 = make_float2(r0.x, -r0.y);   // conj(r0)
    float2 rf3 = make_float2(r1.x, -r1.y);   // conj(r1)
    float2 F00 = make_float2(rf1.x*r0.x - rf1.y*r0.y, rf1.x*r0.y + rf1.y*r0.x);
    float2 F10 = make_float2(rf3.x*r1.x - rf3.y*r1.y, rf3.x*r1.y + rf3.y*r1.x);
    float2 one = make_float2(1.f, 0.f);
    float2* F = (float2*)finals;
    F[0*32+j] = F00; F[1*32+j] = rf1; F[2*32+j] = one;
    F[3*32+j] = F10; F[4*32+j] = rf3; F[5*32+j] = one;
    fl[0*32+j] = F00; fl[1*32+j] = rf1; fl[2*32+j] = one;
    fl[3*32+j] = F10; fl[4*32+j] = rf3; fl[5*32+j] = one;
  }
  __syncthreads();
  for (int idx = t; idx < 1536; idx += 256){
    int pair = idx & 31, k = (idx >> 5) & 7, pi = idx >> 8;   // pi 0..5
    const float* at = (pi >= 3) ? attn1 : attn0;
    float2 f = fl[pi*32 + pair];
    float a0 = at[k*64 + 2*pair], a1 = at[k*64 + 2*pair + 1];
    A[(pi*8+k)*64 + 2*pair]     = (f.x*a0 + f.y*a1) * (1.f/3.f);
    A[(pi*8+k)*64 + 2*pair + 1] = (f.x*a1 - f.y*a0) * (1.f/3.f);
  }
  acc[t] = 0.f;
  if (t < 2) beta[t] = 0.f;
}

// ---- tiled per-type linear: tf[idx[m]] = feat[m] @ W.T + b ----
__global__ __launch_bounds__(256) void k_transform(const float* __restrict__ feat,
                                                   const float* __restrict__ W,
                                                   const float* __restrict__ bias,
                                                   const int* __restrict__ idx,
                                                   int n_nodes, int F,
                                                   float* __restrict__ tf){
  __shared__ float Ax[32][68];
  __shared__ float Bs[32][68];
  int t = threadIdx.x;
  int tx = t & 15;
  int ty = t >> 4;
  int m0 = blockIdx.x * 64;
  int Fq = F >> 2;

  float acc[4][4];
  #pragma unroll
  for (int i = 0; i < 4; ++i)
    #pragma unroll
    for (int j = 0; j < 4; ++j) acc[i][j] = 0.f;

  const float4* feat4 = (const float4*)feat;
  const float4* W4 = (const float4*)W;

  for (int k0 = 0; k0 < F; k0 += 32){
    #pragma unroll
    for (int qq = 0; qq < 2; ++qq){
      int q = t + qq*256;
      int m = q >> 3, kq = q & 7;
      int gm = m0 + m; if (gm > n_nodes - 1) gm = n_nodes - 1;
      float4 v = feat4[(size_t)gm*Fq + (k0 >> 2) + kq];
      Ax[kq*4+0][m] = v.x; Ax[kq*4+1][m] = v.y; Ax[kq*4+2][m] = v.z; Ax[kq*4+3][m] = v.w;
    }
    #pragma unroll
    for (int qq = 0; qq < 2; ++qq){
      int q = t + qq*256;
      int d = q >> 3, kq = q & 7;
      float4 v = W4[(size_t)d*Fq + (k0 >> 2) + kq];
      Bs[kq*4+0][d] = v.x; Bs[kq*4+1][d] = v.y; Bs[kq*4+2][d] = v.z; Bs[kq*4+3][d] = v.w;
    }
    __syncthreads();
    #pragma unroll
    for (int kk = 0; kk < 32; ++kk){
      float4 a = *(const float4*)&Ax[kk][tx*4];
      float4 b = *(const float4*)&Bs[kk][ty*4];
      acc[0][0] += a.x*b.x; acc[0][1] += a.x*b.y; acc[0][2] += a.x*b.z; acc[0][3] += a.x*b.w;
      acc[1][0] += a.y*b.x; acc[1][1] += a.y*b.y; acc[1][2] += a.y*b.z; acc[1][3] += a.y*b.w;
      acc[2][0] += a.z*b.x; acc[2][1] += a.z*b.y; acc[2][2] += a.z*b.z; acc[2][3] += a.z*b.w;
      acc[3][0] += a.w*b.x; acc[3][1] += a.w*b.y; acc[3][2] += a.w*b.z; acc[3][3] += a.w*b.w;
    }
    __syncthreads();
  }

  float4 bv = *(const float4*)&bias[ty*4];
  #pragma unroll
  for (int i = 0; i < 4; ++i){
    int gm = m0 + tx*4 + i;
    if (gm < n_nodes){
      float4 o = make_float4(acc[i][0] + bv.x, acc[i][1] + bv.y,
                             acc[i][2] + bv.z, acc[i][3] + bv.w);
      *(float4*)&tf[(size_t)idx[gm]*HID + ty*4] = o;
    }
  }
}

// ---- P = tf @ A.T per metapath/position, stored f16: P[p][n][i*8+k] ----
__global__ __launch_bounds__(256) void k_pmat(const float* __restrict__ tf,
                                              const float* __restrict__ A,
                                              __half* __restrict__ P){
  __shared__ float tfl[64][65];
  __shared__ float Al[48][65];
  int t = threadIdx.x;
  int n0 = blockIdx.x * 64;
  for (int q = t; q < 3072; q += 256) Al[q >> 6][q & 63] = A[q];
  const float4* tf4 = (const float4*)(tf + (size_t)n0*64);
  for (int q = t; q < 1024; q += 256){
    int n = q >> 4, dq = q & 15;
    float4 v = make_float4(0.f,0.f,0.f,0.f);
    if (n0 + n < NNODES) v = tf4[n*16 + dq];
    tfl[n][dq*4+0]=v.x; tfl[n][dq*4+1]=v.y; tfl[n][dq*4+2]=v.z; tfl[n][dq*4+3]=v.w;
  }
  __syncthreads();
  int nl = t >> 2, q = t & 3;
  float s[12];
  #pragma unroll
  for (int c = 0; c < 12; ++c) s[c] = 0.f;
  #pragma unroll 4
  for (int d = 0; d < 64; ++d){
    float tv = tfl[nl][d];
    #pragma unroll
    for (int c = 0; c < 12; ++c) s[c] += tv * Al[q*12 + c][d];
  }
  int gn = n0 + nl;
  if (gn < NNODES){
    #pragma unroll
    for (int c = 0; c < 12; ++c){
      int cg = q*12 + c;
      int p = cg >= 24;
      int w = cg - p*24;
      P[(size_t)p*2400000 + (size_t)gn*24 + w] = __float2half(s[c]);
    }
  }
}

// ---- zero int buffer ----
__global__ void k_zeroi(int* __restrict__ p, int n){
  int t = blockIdx.x*blockDim.x + threadIdx.x;
  if (t < n) p[t] = 0;
}

// ---- histogram of both metapaths' dst ----
__global__ void k_hist2(const int* __restrict__ d0, const int* __restrict__ d1,
                        int* __restrict__ counts){
  int e = blockIdx.x*blockDim.x + threadIdx.x;
  if (e < NE) atomicAdd(&counts[d0[e]], 1);
  else if (e < 2*NE) atomicAdd(&counts[NG + d1[e-NE]], 1);
}

// ---- exclusive scan over 16384 counts; also zero cursors ----
__global__ __launch_bounds__(1024) void k_scan(const int* __restrict__ counts,
                                               int* __restrict__ offs,
                                               int* __restrict__ curs){
  __shared__ int lds[1024];
  int t = threadIdx.x;
  int base = t*16;
  int v[16]; int sum = 0;
  #pragma unroll
  for (int i = 0; i < 16; ++i){ v[i] = counts[base+i]; sum += v[i]; }
  lds[t] = sum;
  __syncthreads();
  for (int off = 1; off < 1024; off <<= 1){
    int x = (t >= off) ? lds[t-off] : 0;
    __syncthreads();
    lds[t] += x;
    __syncthreads();
  }
  int excl = lds[t] - sum;
  #pragma unroll
  for (int i = 0; i < 16; ++i){ offs[base+i] = excl; excl += v[i]; curs[base+i] = 0; }
  if (t == 1023) offs[2*NG] = excl;
}

// ---- scatter both metapaths' edges into dst-sorted order ----
__global__ void k_scatter2(const int* __restrict__ m0, const int* __restrict__ d0,
                           const int* __restrict__ m1, const int* __restrict__ d1,
                           const int* __restrict__ offs, int* __restrict__ curs,
                           int4* __restrict__ sorted){
  int e = blockIdx.x*blockDim.x + threadIdx.x;
  if (e >= 2*NE) return;
  const int* mp; int d;
  if (e < NE){ mp = m0 + (size_t)e*3; d = d0[e]; }
  else { mp = m1 + (size_t)(e-NE)*3; d = NG + d1[e-NE]; }
  int pos = offs[d] + atomicAdd(&curs[d], 1);
  sorted[pos] = make_int4(mp[0], mp[1], mp[2], 0);
}

// ---- fused per-segment softmax-agg, both metapaths in one grid ----
// phase A: lane-per-edge logits via P-gathers; phase B: half-wave-per-edge agg
__global__ __launch_bounds__(64) void k_seg(const float* __restrict__ tf,
                                            const __half* __restrict__ P,
                                            const int4* __restrict__ sorted,
                                            const int* __restrict__ offs,
                                            const float* __restrict__ finals,
                                            float* __restrict__ ft){
  int bid = blockIdx.x;
  int p = bid >> 13;
  int lane = threadIdx.x;
  int hw = lane >> 5, j = lane & 31;
  int start = offs[bid], end = offs[bid+1];
  float2* ftw = (float2*)(ft + (size_t)bid*512);
  if (start == end){
    #pragma unroll
    for (int kk = 0; kk < 4; ++kk) ftw[(hw*4+kk)*32 + j] = make_float2(0.f, 0.f);
    return;
  }
  const float2* F2 = (const float2*)(finals + p*192);
  float2 f0 = F2[j], f1 = F2[32 + j];
  const float2* tf2 = (const float2*)tf;
  const __half* Pp = P + (size_t)p*2400000;

  __shared__ int4 ndb[64];
  __shared__ float wb[64][8];

  float s[8], ur[8], ui[8];
  #pragma unroll
  for (int k = 0; k < 8; ++k){ s[k] = 0.f; ur[k] = 0.f; ui[k] = 0.f; }

  for (int c = start; c < end; c += 64){
    int n = end - c; if (n > 64) n = 64;
    // ---- phase A: logits ----
    if (lane < n){
      int4 nd = sorted[c + lane];
      ndb[lane] = nd;
      float4 rA = *(const float4*)(Pp + (size_t)nd.x*24);
      float4 rB = *(const float4*)(Pp + (size_t)nd.y*24 + 8);
      float4 rC = *(const float4*)(Pp + (size_t)nd.z*24 + 16);
      const __half2* ha = (const __half2*)&rA;
      const __half2* hb = (const __half2*)&rB;
      const __half2* hc = (const __half2*)&rC;
      float w[8];
      #pragma unroll
      for (int m = 0; m < 4; ++m){
        float2 va = __half22float2(ha[m]);
        float2 vb = __half22float2(hb[m]);
        float2 vc = __half22float2(hc[m]);
        float x0 = va.x + vb.x + vc.x;
        float x1 = va.y + vb.y + vc.y;
        x0 = x0 > 0.f ? x0 : 0.01f*x0;
        x1 = x1 > 0.f ? x1 : 0.01f*x1;
        w[2*m]   = __expf(x0);
        w[2*m+1] = __expf(x1);
      }
      *(float4*)&wb[lane][0] = make_float4(w[0], w[1], w[2], w[3]);
      *(float4*)&wb[lane][4] = make_float4(w[4], w[5], w[6], w[7]);
    }
    __syncthreads();   // 1-wave block: compiles to waitcnt
    // ---- phase B: weighted aggregation, half-wave per edge ----
    int cend = c + n;
    for (int i = c + hw; i < cend; i += 2){
      int e = i - c;
      int4 nd = ndb[e];
      float4 wlo = *(const float4*)&wb[e][0];
      float4 whi = *(const float4*)&wb[e][4];
      float2 v0 = tf2[(size_t)nd.x*32 + j];
      float2 v1 = tf2[(size_t)nd.y*32 + j];
      float2 v2 = tf2[(size_t)nd.z*32 + j];
      float hre = (v0.x*f0.x - v0.y*f0.y) + (v1.x*f1.x - v1.y*f1.y) + v2.x;
      float him = (v0.x*f0.y + v0.y*f0.x) + (v1.x*f1.y + v1.y*f1.x) + v2.y;
      ur[0] += wlo.x*hre; ui[0] += wlo.x*him; s[0] += wlo.x;
      ur[1] += wlo.y*hre; ui[1] += wlo.y*him; s[1] += wlo.y;
      ur[2] += wlo.z*hre; ui[2] += wlo.z*him; s[2] += wlo.z;
      ur[3] += wlo.w*hre; ui[3] += wlo.w*him; s[3] += wlo.w;
      ur[4] += whi.x*hre; ui[4] += whi.x*him; s[4] += whi.x;
      ur[5] += whi.y*hre; ui[5] += whi.y*him; s[5] += whi.y;
      ur[6] += whi.z*hre; ui[6] += whi.z*him; s[6] += whi.z;
      ur[7] += whi.w*hre; ui[7] += whi.w*him; s[7] += whi.w;
    }
    __syncthreads();   // protect ndb/wb before next chunk
  }
  // merge the two half-wave partials
  #pragma unroll
  for (int k = 0; k < 8; ++k){
    ur[k] += __shfl_xor(ur[k], 32);
    ui[k] += __shfl_xor(ui[k], 32);
    s[k]  += __shfl_xor(s[k], 32);
  }
  #pragma unroll
  for (int kk = 0; kk < 4; ++kk){
    int k = hw*4 + kk;
    float inv = 1.f / (3.f * s[k]);
    ftw[k*32 + j] = make_float2(ur[k]*inv, ui[k]*inv);
  }
}

// ---- fused s1 GEMM for both metapaths ----
__global__ __launch_bounds__(256) void k_s1g(const float* __restrict__ ft0,
                                             const float* __restrict__ ft1,
                                             const int* __restrict__ tgt0,
                                             const int* __restrict__ tgt1,
                                             const float* __restrict__ fc1_w,
                                             const float* __restrict__ fc1_b,
                                             float* __restrict__ acc_p){
  int bid = blockIdx.x;
  int bb = bid & 127;
  int db = (bid >> 7) & 1;
  int p  = bid >> 8;
  const float* ft = p ? ft1 : ft0;
  const int* tgt  = p ? tgt1 : tgt0;

  __shared__ float Ax[32][68];
  __shared__ float Bs[32][68];
  __shared__ int   tl[64];
  __shared__ float red[64][16];

  int t = threadIdx.x;
  int tx = t & 15, ty = t >> 4;
  if (t < 64) tl[t] = tgt[bb*64 + t];
  __syncthreads();

  float acc[4][4];
  #pragma unroll
  for (int i = 0; i < 4; ++i)
    #pragma unroll
    for (int j = 0; j < 4; ++j) acc[i][j] = 0.f;

  const float4* W4 = (const float4*)fc1_w;

  for (int k0 = 0; k0 < 512; k0 += 32){
    #pragma unroll
    for (int qq = 0; qq < 2; ++qq){
      int q = t + qq*256;
      int m = q >> 3, kq = q & 7;
      const float4* row = (const float4*)(ft + (size_t)tl[m]*512);
      float4 v = row[(k0 >> 2) + kq];
      v.x = v.x > 0.f ? v.x : expm1f(v.x);
      v.y = v.y > 0.f ? v.y : expm1f(v.y);
      v.z = v.z > 0.f ? v.z : expm1f(v.z);
      v.w = v.w > 0.f ? v.w : expm1f(v.w);
      Ax[kq*4+0][m] = v.x; Ax[kq*4+1][m] = v.y; Ax[kq*4+2][m] = v.z; Ax[kq*4+3][m] = v.w;
    }
    #pragma unroll
    for (int qq = 0; qq < 2; ++qq){
      int q = t + qq*256;
      int d = q >> 3, kq = q & 7;
      float4 v = W4[(size_t)(db*64 + d)*128 + (k0 >> 2) + kq];
      Bs[kq*4+0][d] = v.x; Bs[kq*4+1][d] = v.y; Bs[kq*4+2][d] = v.z; Bs[kq*4+3][d] = v.w;
    }
    __syncthreads();
    #pragma unroll
    for (int kk = 0; kk < 32; ++kk){
      float4 a = *(const float4*)&Ax[kk][tx*4];
      float4 b = *(const float4*)&Bs[kk][ty*4];
      acc[0][0] += a.x*b.x; acc[0][1] += a.x*b.y; acc[0][2] += a.x*b.z; acc[0][3] += a.x*b.w;
      acc[1][0] += a.y*b.x; acc[1][1] += a.y*b.y; acc[1][2] += a.y*b.z; acc[1][3] += a.y*b.w;
      acc[2][0] += a.z*b.x; acc[2][1] += a.z*b.y; acc[2][2] += a.z*b.z; acc[2][3] += a.z*b.w;
      acc[3][0] += a.w*b.x; acc[3][1] += a.w*b.y; acc[3][2] += a.w*b.z; acc[3][3] += a.w*b.w;
    }
    __syncthreads();
  }

  float4 bv = *(const float4*)&fc1_b[db*64 + ty*4];
  float cs0 = 0.f, cs1 = 0.f, cs2 = 0.f, cs3 = 0.f;
  #pragma unroll
  for (int i = 0; i < 4; ++i){
    cs0 += tanhf(acc[i][0] + bv.x);
    cs1 += tanhf(acc[i][1] + bv.y);
    cs2 += tanhf(acc[i][2] + bv.z);
    cs3 += tanhf(acc[i][3] + bv.w);
  }
  red[ty*4+0][tx] = cs0;
  red[ty*4+1][tx] = cs1;
  red[ty*4+2][tx] = cs2;
  red[ty*4+3][tx] = cs3;
  __syncthreads();
  if (t < 64){
    float sv = 0.f;
    #pragma unroll
    for (int x = 0; x < 16; ++x) sv += red[t][x];
    atomicAdd(&acc_p[p*128 + db*64 + t], sv);
  }
}

// ---- beta softmax over 2 metapaths ----
__global__ void k_beta(const float* __restrict__ acc, const float* __restrict__ fc2_w,
                       float* __restrict__ beta){
  int t = threadIdx.x;  // 64
  float s0 = acc[t]*fc2_w[t] + acc[t+64]*fc2_w[t+64];
  float s1 = acc[128+t]*fc2_w[t] + acc[192+t]*fc2_w[t+64];
  #pragma unroll
  for (int mask = 1; mask < 64; mask <<= 1){
    s0 += __shfl_xor(s0, mask, 64);
    s1 += __shfl_xor(s1, mask, 64);
  }
  if (t == 0){
    float z0 = s0 / (float)NB, z1 = s1 / (float)NB;
    float mz = fmaxf(z0, z1);
    float e0 = expf(z0 - mz), e1 = expf(z1 - mz);
    float inv = 1.f / (e0 + e1);
    beta[0] = e0*inv; beta[1] = e1*inv;
  }
}

// ---- hagg + logits (gather + elu fused) ----
__global__ void k_final(const float* __restrict__ ft0, const float* __restrict__ ft1,
                        const int* __restrict__ tgt0, const int* __restrict__ tgt1,
                        const float* __restrict__ beta, const float* __restrict__ fc_w,
                        const float* __restrict__ fc_b, float* __restrict__ d_out){
  __shared__ float lds[512];
  int b = blockIdx.x, t = threadIdx.x;  // 512 threads
  float b0 = beta[0], b1 = beta[1];
  int g0 = tgt0[b], g1 = tgt1[b];
  float v0 = ft0[(size_t)g0*512 + t]; v0 = v0 > 0.f ? v0 : expm1f(v0);
  float v1 = ft1[(size_t)g1*512 + t]; v1 = v1 > 0.f ? v1 : expm1f(v1);
  float h = b0*v0 + b1*v1;
  lds[t] = h;
  d_out[(size_t)NB*OUTD + (size_t)b*512 + t] = h;
  __syncthreads();
  int o = t >> 5, j = t & 31;
  float s = 0.f;
  const float* w = fc_w + o*512;
  for (int d = j; d < 512; d += 32) s += lds[d]*w[d];
  #pragma unroll
  for (int mask = 1; mask < 32; mask <<= 1) s += __shfl_xor(s, mask, 32);
  if (j == 0) d_out[(size_t)b*OUTD + o] = s + fc_b[o];
}

extern "C" void kernel_launch(void* const* d_in, const int* in_sizes, int n_in,
                              void* d_out, int out_size, void* d_ws, size_t ws_size,
                              hipStream_t stream){
  const float* feat0  = (const float*)d_in[0];
  const float* feat1  = (const float*)d_in[1];
  const float* W0     = (const float*)d_in[2];
  const float* b0     = (const float*)d_in[3];
  const float* W1     = (const float*)d_in[4];
  const float* b1     = (const float*)d_in[5];
  const float* r_vec  = (const float*)d_in[6];
  const float* attn0  = (const float*)d_in[7];
  const float* attn1  = (const float*)d_in[8];
  const float* fc1_w  = (const float*)d_in[9];
  const float* fc1_b  = (const float*)d_in[10];
  const float* fc2_w  = (const float*)d_in[11];
  const float* fc_w   = (const float*)d_in[12];
  const float* fc_b   = (const float*)d_in[13];
  const int*   idx0   = (const int*)d_in[14];
  const int*   idx1   = (const int*)d_in[15];
  const int*   mpi0   = (const int*)d_in[16];
  const int*   mdst0  = (const int*)d_in[17];
  const int*   mtgt0  = (const int*)d_in[18];
  const int*   mpi1   = (const int*)d_in[19];
  const int*   mdst1  = (const int*)d_in[20];
  const int*   mtgt1  = (const int*)d_in[21];

  float* ws      = (float*)d_ws;
  float* tf      = ws + OFF_TF;
  float* finals  = ws + OFF_FINALS;
  float* Amat    = ws + OFF_A;
  float* acc     = ws + OFF_ACC;
  float* beta    = ws + OFF_BETA;
  __half* P      = (__half*)(ws + OFF_P);
  int4*  sorted  = (int4*)(ws + OFF_SORTED);
  int*   counts  = (int*)(ws + OFF_COUNTS);
  int*   curs    = (int*)(ws + OFF_CURS);
  int*   offs    = (int*)(ws + OFF_OFFS);
  float* ft0     = ws + OFF_FT;
  float* ft1     = ws + OFF_FT + (size_t)NG*512;

  k_prep<<<1, 256, 0, stream>>>(r_vec, attn0, attn1, finals, Amat, acc, beta);
  k_transform<<<(NT0 + 63)/64, 256, 0, stream>>>(feat0, W0, b0, idx0, NT0, FD0, tf);
  k_transform<<<(NT1 + 63)/64, 256, 0, stream>>>(feat1, W1, b1, idx1, NT1, FD1, tf);
  k_pmat<<<(NNODES + 63)/64, 256, 0, stream>>>(tf, Amat, P);

  k_zeroi<<<64, 256, 0, stream>>>(counts, 2*NG);
  k_hist2<<<(2*NE + 255)/256, 256, 0, stream>>>(mdst0, mdst1, counts);
  k_scan<<<1, 1024, 0, stream>>>(counts, offs, curs);
  k_scatter2<<<(2*NE + 255)/256, 256, 0, stream>>>(mpi0, mdst0, mpi1, mdst1,
                                                   offs, curs, sorted);
  k_seg<<<2*NG, 64, 0, stream>>>(tf, P, sorted, offs, finals, ws + OFF_FT);

  k_s1g<<<512, 256, 0, stream>>>(ft0, ft1, mtgt0, mtgt1, fc1_w, fc1_b, acc);
  k_beta<<<1, 64, 0, stream>>>(acc, fc2_w, beta);
  k_final<<<NB, 512, 0, stream>>>(ft0, ft1, mtgt0, mtgt1, beta, fc_w, fc_b,
                                  (float*)d_out);
}

// Round 6
// 262.631 us; speedup vs baseline: 10.3160x; 1.1213x over previous
//
#include <hip/hip_runtime.h>
#include <hip/hip_fp16.h>
#include <math.h>

#define NNODES 100000
#define NT0 60000
#define NT1 40000
#define FD0 128
#define FD1 64
#define HID 64
#define HEADS 8
#define OUTD 16
#define AVEC 128
#define NE 250000
#define NG 8192
#define NB 8192

// workspace layout (float offsets)
#define OFF_TF16    0ull          // 100000*64 halves = 3,200,000 floats
#define OFF_FINALS  3200000ull    // 512
#define OFF_A       3200512ull    // 3,072
#define OFF_ACC     3203584ull    // 256
#define OFF_BETA    3203840ull    // 256
#define OFF_P       3204096ull    // 2,400,000 floats = 4,800,000 halves
#define OFF_SORTED  5604096ull    // 2,000,000 (500,000 int4; byte off % 16 == 0)
#define OFF_COUNTS  7604096ull    // 16,384
#define OFF_CURS    7620480ull    // 16,384
#define OFF_OFFS    7636864ull    // 16,640 (16,385 used)
#define OFF_FT      7653504ull    // 2*NG*512 = 8,388,608
// total = 16,042,112 floats = 64.2 MB

// ---- prep: finals + logit-projection matrices A, zero acc ----
__global__ __launch_bounds__(256) void k_prep(const float* __restrict__ r_vec,
                       const float* __restrict__ attn0, const float* __restrict__ attn1,
                       float* __restrict__ finals, float* __restrict__ A,
                       float* __restrict__ acc, float* __restrict__ beta){
  __shared__ float2 fl[192];   // [pi][pair]
  int t = threadIdx.x;
  if (t < 32){
    int j = t;
    const float2* rv = (const float2*)r_vec;
    float2 r0 = rv[j];
    float2 r1 = rv[32 + j];
    float n0 = rsqrtf(r0.x*r0.x + r0.y*r0.y);
    float n1 = rsqrtf(r1.x*r1.x + r1.y*r1.y);
    r0.x *= n0; r0.y *= n0; r1.x *= n1; r1.y *= n1;
    float2 rf1 = make_float2(r0.x, -r0.y);   // conj(r0)
    float2 rf3 = make_float2(r1.x, -r1.y);   // conj(r1)
    float2 F00 = make_float2(rf1.x*r0.x - rf1.y*r0.y, rf1.x*r0.y + rf1.y*r0.x);
    float2 F10 = make_float2(rf3.x*r1.x - rf3.y*r1.y, rf3.x*r1.y + rf3.y*r1.x);
    float2 one = make_float2(1.f, 0.f);
    float2* F = (float2*)finals;
    F[0*32+j] = F00; F[1*32+j] = rf1; F[2*32+j] = one;
    F[3*32+j] = F10; F[4*32+j] = rf3; F[5*32+j] = one;
    fl[0*32+j] = F00; fl[1*32+j] = rf1; fl[2*32+j] = one;
    fl[3*32+j] = F10; fl[4*32+j] = rf3; fl[5*32+j] = one;
  }
  __syncthreads();
  for (int idx = t; idx < 1536; idx += 256){
    int pair = idx & 31, k = (idx >> 5) & 7, pi = idx >> 8;   // pi 0..5
    const float* at = (pi >= 3) ? attn1 : attn0;
    float2 f = fl[pi*32 + pair];
    float a0 = at[k*64 + 2*pair], a1 = at[k*64 + 2*pair + 1];
    A[(pi*8+k)*64 + 2*pair]     = (f.x*a0 + f.y*a1) * (1.f/3.f);
    A[(pi*8+k)*64 + 2*pair + 1] = (f.x*a1 - f.y*a0) * (1.f/3.f);
  }
  acc[t] = 0.f;
  if (t < 2) beta[t] = 0.f;
}

// ---- merged per-type linear: tf16[idx[m]] = f16(feat[m] @ W.T + b) ----
__global__ __launch_bounds__(256) void k_transform2(const float* __restrict__ feat0,
                  const float* __restrict__ W0v, const float* __restrict__ b0v,
                  const int* __restrict__ idx0,
                  const float* __restrict__ feat1, const float* __restrict__ W1v,
                  const float* __restrict__ b1v, const int* __restrict__ idx1,
                  __half* __restrict__ tf16){
  __shared__ float Ax[32][68];
  __shared__ float Bs[32][68];
  const int nb0 = (NT0 + 63)/64;
  int bid = blockIdx.x;
  const float *feat, *W, *bias; const int* idx; int n_nodes, F, m0;
  if (bid < nb0){ feat=feat0; W=W0v; bias=b0v; idx=idx0; n_nodes=NT0; F=FD0; m0=bid*64; }
  else { feat=feat1; W=W1v; bias=b1v; idx=idx1; n_nodes=NT1; F=FD1; m0=(bid-nb0)*64; }
  int t = threadIdx.x;
  int tx = t & 15;
  int ty = t >> 4;
  int Fq = F >> 2;

  float acc[4][4];
  #pragma unroll
  for (int i = 0; i < 4; ++i)
    #pragma unroll
    for (int j = 0; j < 4; ++j) acc[i][j] = 0.f;

  const float4* feat4 = (const float4*)feat;
  const float4* W4 = (const float4*)W;

  for (int k0 = 0; k0 < F; k0 += 32){
    #pragma unroll
    for (int qq = 0; qq < 2; ++qq){
      int q = t + qq*256;
      int m = q >> 3, kq = q & 7;
      int gm = m0 + m; if (gm > n_nodes - 1) gm = n_nodes - 1;
      float4 v = feat4[(size_t)gm*Fq + (k0 >> 2) + kq];
      Ax[kq*4+0][m] = v.x; Ax[kq*4+1][m] = v.y; Ax[kq*4+2][m] = v.z; Ax[kq*4+3][m] = v.w;
    }
    #pragma unroll
    for (int qq = 0; qq < 2; ++qq){
      int q = t + qq*256;
      int d = q >> 3, kq = q & 7;
      float4 v = W4[(size_t)d*Fq + (k0 >> 2) + kq];
      Bs[kq*4+0][d] = v.x; Bs[kq*4+1][d] = v.y; Bs[kq*4+2][d] = v.z; Bs[kq*4+3][d] = v.w;
    }
    __syncthreads();
    #pragma unroll
    for (int kk = 0; kk < 32; ++kk){
      float4 a = *(const float4*)&Ax[kk][tx*4];
      float4 b = *(const float4*)&Bs[kk][ty*4];
      acc[0][0] += a.x*b.x; acc[0][1] += a.x*b.y; acc[0][2] += a.x*b.z; acc[0][3] += a.x*b.w;
      acc[1][0] += a.y*b.x; acc[1][1] += a.y*b.y; acc[1][2] += a.y*b.z; acc[1][3] += a.y*b.w;
      acc[2][0] += a.z*b.x; acc[2][1] += a.z*b.y; acc[2][2] += a.z*b.z; acc[2][3] += a.z*b.w;
      acc[3][0] += a.w*b.x; acc[3][1] += a.w*b.y; acc[3][2] += a.w*b.z; acc[3][3] += a.w*b.w;
    }
    __syncthreads();
  }

  float4 bv = *(const float4*)&bias[ty*4];
  #pragma unroll
  for (int i = 0; i < 4; ++i){
    int gm = m0 + tx*4 + i;
    if (gm < n_nodes){
      union { __half2 h2[2]; uint2 u; } pk;
      pk.h2[0] = __floats2half2_rn(acc[i][0] + bv.x, acc[i][1] + bv.y);
      pk.h2[1] = __floats2half2_rn(acc[i][2] + bv.z, acc[i][3] + bv.w);
      *(uint2*)&tf16[(size_t)idx[gm]*HID + ty*4] = pk.u;
    }
  }
}

// ---- P = tf16 @ A.T per metapath/position, stored f16: P[p][n][i*8+k] ----
__global__ __launch_bounds__(256) void k_pmat(const __half* __restrict__ tf16,
                                              const float* __restrict__ A,
                                              __half* __restrict__ P){
  __shared__ float tfl[64][65];
  __shared__ float Al[48][65];
  int t = threadIdx.x;
  int n0 = blockIdx.x * 64;
  for (int q = t; q < 3072; q += 256) Al[q >> 6][q & 63] = A[q];
  const __half2* tfh = (const __half2*)(tf16 + (size_t)n0*64);
  for (int q = t; q < 2048; q += 256){
    int n = q >> 5, dq = q & 31;
    float2 v = make_float2(0.f, 0.f);
    if (n0 + n < NNODES) v = __half22float2(tfh[n*32 + dq]);
    tfl[n][dq*2] = v.x; tfl[n][dq*2+1] = v.y;
  }
  __syncthreads();
  int nl = t >> 2, q = t & 3;
  float s[12];
  #pragma unroll
  for (int c = 0; c < 12; ++c) s[c] = 0.f;
  #pragma unroll 4
  for (int d = 0; d < 64; ++d){
    float tv = tfl[nl][d];
    #pragma unroll
    for (int c = 0; c < 12; ++c) s[c] += tv * Al[q*12 + c][d];
  }
  int gn = n0 + nl;
  if (gn < NNODES){
    #pragma unroll
    for (int c = 0; c < 12; ++c){
      int cg = q*12 + c;
      int p = cg >= 24;
      int w = cg - p*24;
      P[(size_t)p*2400000 + (size_t)gn*24 + w] = __float2half(s[c]);
    }
  }
}

// ---- zero int buffer ----
__global__ void k_zeroi(int* __restrict__ p, int n){
  int t = blockIdx.x*blockDim.x + threadIdx.x;
  if (t < n) p[t] = 0;
}

// ---- histogram of both metapaths' dst ----
__global__ void k_hist2(const int* __restrict__ d0, const int* __restrict__ d1,
                        int* __restrict__ counts){
  int e = blockIdx.x*blockDim.x + threadIdx.x;
  if (e < NE) atomicAdd(&counts[d0[e]], 1);
  else if (e < 2*NE) atomicAdd(&counts[NG + d1[e-NE]], 1);
}

// ---- exclusive scan over 16384 counts; also zero cursors ----
__global__ __launch_bounds__(1024) void k_scan(const int* __restrict__ counts,
                                               int* __restrict__ offs,
                                               int* __restrict__ curs){
  __shared__ int lds[1024];
  int t = threadIdx.x;
  int base = t*16;
  int v[16]; int sum = 0;
  #pragma unroll
  for (int i = 0; i < 16; ++i){ v[i] = counts[base+i]; sum += v[i]; }
  lds[t] = sum;
  __syncthreads();
  for (int off = 1; off < 1024; off <<= 1){
    int x = (t >= off) ? lds[t-off] : 0;
    __syncthreads();
    lds[t] += x;
    __syncthreads();
  }
  int excl = lds[t] - sum;
  #pragma unroll
  for (int i = 0; i < 16; ++i){ offs[base+i] = excl; excl += v[i]; curs[base+i] = 0; }
  if (t == 1023) offs[2*NG] = excl;
}

// ---- scatter both metapaths' edges into dst-sorted order ----
__global__ void k_scatter2(const int* __restrict__ m0, const int* __restrict__ d0,
                           const int* __restrict__ m1, const int* __restrict__ d1,
                           const int* __restrict__ offs, int* __restrict__ curs,
                           int4* __restrict__ sorted){
  int e = blockIdx.x*blockDim.x + threadIdx.x;
  if (e >= 2*NE) return;
  const int* mp; int d;
  if (e < NE){ mp = m0 + (size_t)e*3; d = d0[e]; }
  else { mp = m1 + (size_t)(e-NE)*3; d = NG + d1[e-NE]; }
  int pos = offs[d] + atomicAdd(&curs[d], 1);
  sorted[pos] = make_int4(mp[0], mp[1], mp[2], 0);
}

// ---- fused per-segment softmax-agg, both metapaths in one grid ----
__global__ __launch_bounds__(64) void k_seg(const __half* __restrict__ tf16,
                                            const __half* __restrict__ P,
                                            const int4* __restrict__ sorted,
                                            const int* __restrict__ offs,
                                            const float* __restrict__ finals,
                                            float* __restrict__ ft){
  int bid = blockIdx.x;
  int p = bid >> 13;
  int lane = threadIdx.x;
  int hw = lane >> 5, j = lane & 31;
  int start = offs[bid], end = offs[bid+1];
  float2* ftw = (float2*)(ft + (size_t)bid*512);
  if (start == end){
    #pragma unroll
    for (int kk = 0; kk < 4; ++kk) ftw[(hw*4+kk)*32 + j] = make_float2(0.f, 0.f);
    return;
  }
  const float2* F2 = (const float2*)(finals + p*192);
  float2 f0 = F2[j], f1 = F2[32 + j];
  const __half2* tfh = (const __half2*)tf16;
  const __half* Pp = P + (size_t)p*2400000;

  __shared__ int4 ndb[64];
  __shared__ float wb[64][8];

  float s[8], ur[8], ui[8];
  #pragma unroll
  for (int k = 0; k < 8; ++k){ s[k] = 0.f; ur[k] = 0.f; ui[k] = 0.f; }

  for (int c = start; c < end; c += 64){
    int n = end - c; if (n > 64) n = 64;
    // ---- phase A: logits (lane-per-edge) ----
    if (lane < n){
      int4 nd = sorted[c + lane];
      ndb[lane] = nd;
      float4 rA = *(const float4*)(Pp + (size_t)nd.x*24);
      float4 rB = *(const float4*)(Pp + (size_t)nd.y*24 + 8);
      float4 rC = *(const float4*)(Pp + (size_t)nd.z*24 + 16);
      const __half2* ha = (const __half2*)&rA;
      const __half2* hb = (const __half2*)&rB;
      const __half2* hc = (const __half2*)&rC;
      float w[8];
      #pragma unroll
      for (int m = 0; m < 4; ++m){
        float2 va = __half22float2(ha[m]);
        float2 vb = __half22float2(hb[m]);
        float2 vc = __half22float2(hc[m]);
        float x0 = va.x + vb.x + vc.x;
        float x1 = va.y + vb.y + vc.y;
        x0 = x0 > 0.f ? x0 : 0.01f*x0;
        x1 = x1 > 0.f ? x1 : 0.01f*x1;
        w[2*m]   = __expf(x0);
        w[2*m+1] = __expf(x1);
      }
      *(float4*)&wb[lane][0] = make_float4(w[0], w[1], w[2], w[3]);
      *(float4*)&wb[lane][4] = make_float4(w[4], w[5], w[6], w[7]);
    }
    __syncthreads();
    // ---- phase B: weighted aggregation (half-wave per edge) ----
    int cend = c + n;
    for (int i = c + hw; i < cend; i += 2){
      int e = i - c;
      int4 nd = ndb[e];
      float4 wlo = *(const float4*)&wb[e][0];
      float4 whi = *(const float4*)&wb[e][4];
      float2 v0 = __half22float2(tfh[(size_t)nd.x*32 + j]);
      float2 v1 = __half22float2(tfh[(size_t)nd.y*32 + j]);
      float2 v2 = __half22float2(tfh[(size_t)nd.z*32 + j]);
      float hre = (v0.x*f0.x - v0.y*f0.y) + (v1.x*f1.x - v1.y*f1.y) + v2.x;
      float him = (v0.x*f0.y + v0.y*f0.x) + (v1.x*f1.y + v1.y*f1.x) + v2.y;
      ur[0] += wlo.x*hre; ui[0] += wlo.x*him; s[0] += wlo.x;
      ur[1] += wlo.y*hre; ui[1] += wlo.y*him; s[1] += wlo.y;
      ur[2] += wlo.z*hre; ui[2] += wlo.z*him; s[2] += wlo.z;
      ur[3] += wlo.w*hre; ui[3] += wlo.w*him; s[3] += wlo.w;
      ur[4] += whi.x*hre; ui[4] += whi.x*him; s[4] += whi.x;
      ur[5] += whi.y*hre; ui[5] += whi.y*him; s[5] += whi.y;
      ur[6] += whi.z*hre; ui[6] += whi.z*him; s[6] += whi.z;
      ur[7] += whi.w*hre; ui[7] += whi.w*him; s[7] += whi.w;
    }
    __syncthreads();
  }
  #pragma unroll
  for (int k = 0; k < 8; ++k){
    ur[k] += __shfl_xor(ur[k], 32);
    ui[k] += __shfl_xor(ui[k], 32);
    s[k]  += __shfl_xor(s[k], 32);
  }
  #pragma unroll
  for (int kk = 0; kk < 4; ++kk){
    int k = hw*4 + kk;
    float inv = 1.f / (3.f * s[k]);
    ftw[k*32 + j] = make_float2(ur[k]*inv, ui[k]*inv);
  }
}

// ---- fused s1 GEMM for both metapaths: 64x128 tile, 512 threads ----
__global__ __launch_bounds__(512) void k_s1g(const float* __restrict__ ft0,
                                             const float* __restrict__ ft1,
                                             const int* __restrict__ tgt0,
                                             const int* __restrict__ tgt1,
                                             const float* __restrict__ fc1_w,
                                             const float* __restrict__ fc1_b,
                                             float* __restrict__ acc_p){
  int bid = blockIdx.x;
  int bb = bid & 127;
  int p  = bid >> 7;
  const float* ft = p ? ft1 : ft0;
  const int* tgt  = p ? tgt1 : tgt0;

  __shared__ float Ax[32][68];
  __shared__ float Bs[32][132];
  __shared__ int   tl[64];
  __shared__ float red[128][17];

  int t = threadIdx.x;
  int tx = t & 15, ty = t >> 4;   // tx: 16 row-groups x4, ty: 32 dim-groups x4
  if (t < 64) tl[t] = tgt[bb*64 + t];
  __syncthreads();

  float acc[4][4];
  #pragma unroll
  for (int i = 0; i < 4; ++i)
    #pragma unroll
    for (int j = 0; j < 4; ++j) acc[i][j] = 0.f;

  const float4* W4 = (const float4*)fc1_w;   // [128][128 float4]

  for (int k0 = 0; k0 < 512; k0 += 32){
    {
      int m = t >> 3, kq = t & 7;   // 512 float4, 1 per thread
      const float4* row = (const float4*)(ft + (size_t)tl[m]*512);
      float4 v = row[(k0 >> 2) + kq];
      v.x = v.x > 0.f ? v.x : expm1f(v.x);
      v.y = v.y > 0.f ? v.y : expm1f(v.y);
      v.z = v.z > 0.f ? v.z : expm1f(v.z);
      v.w = v.w > 0.f ? v.w : expm1f(v.w);
      Ax[kq*4+0][m] = v.x; Ax[kq*4+1][m] = v.y; Ax[kq*4+2][m] = v.z; Ax[kq*4+3][m] = v.w;
    }
    #pragma unroll
    for (int qq = 0; qq < 2; ++qq){
      int q = t + qq*512;
      int d = q >> 3, kq = q & 7;   // 1024 float4, 2 per thread
      float4 v = W4[(size_t)d*128 + (k0 >> 2) + kq];
      Bs[kq*4+0][d] = v.x; Bs[kq*4+1][d] = v.y; Bs[kq*4+2][d] = v.z; Bs[kq*4+3][d] = v.w;
    }
    __syncthreads();
    #pragma unroll
    for (int kk = 0; kk < 32; ++kk){
      float4 a = *(const float4*)&Ax[kk][tx*4];
      float4 b = *(const float4*)&Bs[kk][ty*4];
      acc[0][0] += a.x*b.x; acc[0][1] += a.x*b.y; acc[0][2] += a.x*b.z; acc[0][3] += a.x*b.w;
      acc[1][0] += a.y*b.x; acc[1][1] += a.y*b.y; acc[1][2] += a.y*b.z; acc[1][3] += a.y*b.w;
      acc[2][0] += a.z*b.x; acc[2][1] += a.z*b.y; acc[2][2] += a.z*b.z; acc[2][3] += a.z*b.w;
      acc[3][0] += a.w*b.x; acc[3][1] += a.w*b.y; acc[3][2] += a.w*b.z; acc[3][3] += a.w*b.w;
    }
    __syncthreads();
  }

  float4 bv = *(const float4*)&fc1_b[ty*4];
  float cs0 = 0.f, cs1 = 0.f, cs2 = 0.f, cs3 = 0.f;
  #pragma unroll
  for (int i = 0; i < 4; ++i){
    cs0 += tanhf(acc[i][0] + bv.x);
    cs1 += tanhf(acc[i][1] + bv.y);
    cs2 += tanhf(acc[i][2] + bv.z);
    cs3 += tanhf(acc[i][3] + bv.w);
  }
  red[ty*4+0][tx] = cs0;
  red[ty*4+1][tx] = cs1;
  red[ty*4+2][tx] = cs2;
  red[ty*4+3][tx] = cs3;
  __syncthreads();
  if (t < 128){
    float sv = 0.f;
    #pragma unroll
    for (int x = 0; x < 16; ++x) sv += red[t][x];
    atomicAdd(&acc_p[p*128 + t], sv);
  }
}

// ---- beta softmax over 2 metapaths ----
__global__ void k_beta(const float* __restrict__ acc, const float* __restrict__ fc2_w,
                       float* __restrict__ beta){
  int t = threadIdx.x;  // 64
  float s0 = acc[t]*fc2_w[t] + acc[t+64]*fc2_w[t+64];
  float s1 = acc[128+t]*fc2_w[t] + acc[192+t]*fc2_w[t+64];
  #pragma unroll
  for (int mask = 1; mask < 64; mask <<= 1){
    s0 += __shfl_xor(s0, mask, 64);
    s1 += __shfl_xor(s1, mask, 64);
  }
  if (t == 0){
    float z0 = s0 / (float)NB, z1 = s1 / (float)NB;
    float mz = fmaxf(z0, z1);
    float e0 = expf(z0 - mz), e1 = expf(z1 - mz);
    float inv = 1.f / (e0 + e1);
    beta[0] = e0*inv; beta[1] = e1*inv;
  }
}

// ---- hagg + logits (gather + elu fused) ----
__global__ void k_final(const float* __restrict__ ft0, const float* __restrict__ ft1,
                        const int* __restrict__ tgt0, const int* __restrict__ tgt1,
                        const float* __restrict__ beta, const float* __restrict__ fc_w,
                        const float* __restrict__ fc_b, float* __restrict__ d_out){
  __shared__ float lds[512];
  int b = blockIdx.x, t = threadIdx.x;  // 512 threads
  float b0 = beta[0], b1 = beta[1];
  int g0 = tgt0[b], g1 = tgt1[b];
  float v0 = ft0[(size_t)g0*512 + t]; v0 = v0 > 0.f ? v0 : expm1f(v0);
  float v1 = ft1[(size_t)g1*512 + t]; v1 = v1 > 0.f ? v1 : expm1f(v1);
  float h = b0*v0 + b1*v1;
  lds[t] = h;
  d_out[(size_t)NB*OUTD + (size_t)b*512 + t] = h;
  __syncthreads();
  int o = t >> 5, j = t & 31;
  float s = 0.f;
  const float* w = fc_w + o*512;
  for (int d = j; d < 512; d += 32) s += lds[d]*w[d];
  #pragma unroll
  for (int mask = 1; mask < 32; mask <<= 1) s += __shfl_xor(s, mask, 32);
  if (j == 0) d_out[(size_t)b*OUTD + o] = s + fc_b[o];
}

extern "C" void kernel_launch(void* const* d_in, const int* in_sizes, int n_in,
                              void* d_out, int out_size, void* d_ws, size_t ws_size,
                              hipStream_t stream){
  const float* feat0  = (const float*)d_in[0];
  const float* feat1  = (const float*)d_in[1];
  const float* W0     = (const float*)d_in[2];
  const float* b0     = (const float*)d_in[3];
  const float* W1     = (const float*)d_in[4];
  const float* b1     = (const float*)d_in[5];
  const float* r_vec  = (const float*)d_in[6];
  const float* attn0  = (const float*)d_in[7];
  const float* attn1  = (const float*)d_in[8];
  const float* fc1_w  = (const float*)d_in[9];
  const float* fc1_b  = (const float*)d_in[10];
  const float* fc2_w  = (const float*)d_in[11];
  const float* fc_w   = (const float*)d_in[12];
  const float* fc_b   = (const float*)d_in[13];
  const int*   idx0   = (const int*)d_in[14];
  const int*   idx1   = (const int*)d_in[15];
  const int*   mpi0   = (const int*)d_in[16];
  const int*   mdst0  = (const int*)d_in[17];
  const int*   mtgt0  = (const int*)d_in[18];
  const int*   mpi1   = (const int*)d_in[19];
  const int*   mdst1  = (const int*)d_in[20];
  const int*   mtgt1  = (const int*)d_in[21];

  float* ws      = (float*)d_ws;
  __half* tf16   = (__half*)(ws + OFF_TF16);
  float* finals  = ws + OFF_FINALS;
  float* Amat    = ws + OFF_A;
  float* acc     = ws + OFF_ACC;
  float* beta    = ws + OFF_BETA;
  __half* P      = (__half*)(ws + OFF_P);
  int4*  sorted  = (int4*)(ws + OFF_SORTED);
  int*   counts  = (int*)(ws + OFF_COUNTS);
  int*   curs    = (int*)(ws + OFF_CURS);
  int*   offs    = (int*)(ws + OFF_OFFS);
  float* ft0     = ws + OFF_FT;
  float* ft1     = ws + OFF_FT + (size_t)NG*512;

  k_prep<<<1, 256, 0, stream>>>(r_vec, attn0, attn1, finals, Amat, acc, beta);
  k_zeroi<<<64, 256, 0, stream>>>(counts, 2*NG);
  k_hist2<<<(2*NE + 255)/256, 256, 0, stream>>>(mdst0, mdst1, counts);
  k_scan<<<1, 1024, 0, stream>>>(counts, offs, curs);
  k_scatter2<<<(2*NE + 255)/256, 256, 0, stream>>>(mpi0, mdst0, mpi1, mdst1,
                                                   offs, curs, sorted);

  k_transform2<<<(NT0 + 63)/64 + (NT1 + 63)/64, 256, 0, stream>>>(
      feat0, W0, b0, idx0, feat1, W1, b1, idx1, tf16);
  k_pmat<<<(NNODES + 63)/64, 256, 0, stream>>>(tf16, Amat, P);

  k_seg<<<2*NG, 64, 0, stream>>>(tf16, P, sorted, offs, finals, ws + OFF_FT);

  k_s1g<<<256, 512, 0, stream>>>(ft0, ft1, mtgt0, mtgt1, fc1_w, fc1_b, acc);
  k_beta<<<1, 64, 0, stream>>>(acc, fc2_w, beta);
  k_final<<<NB, 512, 0, stream>>>(ft0, ft1, mtgt0, mtgt1, beta, fc_w, fc_b,
                                  (float*)d_out);
}